// Round 5
// baseline (840.043 us; speedup 1.0000x reference)
//
#include <hip/hip_runtime.h>
#include <hip/hip_bf16.h>

#define NNODES 32
#define TSTEPS 49
#define NEDGE  992
#define ROWS_E 7936     // B*E
#define ROWS_OUT 12544  // B*T*N
#define EPSV 1e-5f

typedef __hip_bfloat16 bf16;
typedef __attribute__((ext_vector_type(8))) short bf16x8;
typedef __attribute__((ext_vector_type(4))) float f32x4;

__device__ inline float eluf(float x){ return x > 0.f ? x : (__expf(x) - 1.f); }
__device__ inline float bfu2f(unsigned short u){ unsigned v = ((unsigned)u) << 16; return *reinterpret_cast<float*>(&v); }
__device__ inline unsigned cvt_pk_bf16(float lo, float hi){
  unsigned r;
  asm("v_cvt_pk_bf16_f32 %0, %1, %2" : "=v"(r) : "v"(lo), "v"(hi));
  return r;
}

// ---------------- weight prep: transpose + bf16 convert + bias builds ----------------
__global__ void prep_weights(const float* e2w1, const float* e2w2, const float* e4w1, const float* e4w2,
                             const float* mw2, const float* ow1, const float* ow2,
                             const float* e2b1, const float* e4b1,
                             bf16* w2abT, bf16* w2bT, bf16* w4abT, bf16* w4cT, bf16* w4bT,
                             bf16* mw2T, bf16* ow1T, bf16* ow2T,
                             float* bias2, float* bias4, float* zerob){
  int i = blockIdx.x*256 + threadIdx.x;
  if (i < 131072){ int n=i>>8, c=i&255;
    w2abT[i] = __float2bfloat16(n<256 ? e2w1[c*256+n] : e2w1[(256+c)*256 + (n-256)]); return;} i-=131072;
  if (i < 65536){ int n=i>>8,c=i&255; w2bT[i]=__float2bfloat16(e2w2[c*256+n]); return;} i-=65536;
  if (i < 131072){ int n=i>>8,c=i&255;
    w4abT[i]=__float2bfloat16(n<256 ? e4w1[c*256+n] : e4w1[(256+c)*256+(n-256)]); return;} i-=131072;
  if (i < 65536){ int n=i>>8,c=i&255; w4cT[i]=__float2bfloat16(e4w1[(512+c)*256+n]); return;} i-=65536;
  if (i < 65536){ int n=i>>8,c=i&255; w4bT[i]=__float2bfloat16(e4w2[c*256+n]); return;} i-=65536;
  if (i < 262144){ int k=i>>16, r=i&65535; int n=r>>8,c=r&255;
    mw2T[i]=__float2bfloat16(mw2[(k*256+c)*256+n]); return;} i-=262144;
  if (i < 73728){ int n=i/288, c=i%288;
    ow1T[i]= (c<260)?__float2bfloat16(ow1[c*256+n]):__float2bfloat16(0.f); return;} i-=73728;
  if (i < 65536){ int n=i>>8,c=i&255; ow2T[i]=__float2bfloat16(ow2[c*256+n]); return;} i-=65536;
  if (i < 512){ bias2[i] = (i<256)?e2b1[i]:0.f; return;} i-=512;
  if (i < 512){ bias4[i] = (i<256)?e4b1[i]:0.f; return;} i-=512;
  if (i < 256){ zerob[i]=0.f; return; }
}

// ---------------- small 2-layer ELU MLP (256 rows), fp32 VALU ----------------
template<int KIN>
__global__ void small_mlp(const float* __restrict__ X, const float* __restrict__ w1, const float* __restrict__ b1,
                          const float* __restrict__ w2, const float* __restrict__ b2, float* __restrict__ H){
  __shared__ float xs[KIN];
  __shared__ float h1[256];
  int r = blockIdx.x, f = threadIdx.x;
  for (int c = f; c < KIN; c += 256) xs[c] = X[(size_t)r*KIN + c];
  __syncthreads();
  float acc = b1[f];
  for (int c = 0; c < KIN; c++) acc = fmaf(xs[c], w1[c*256+f], acc);
  h1[f] = eluf(acc);
  __syncthreads();
  float a2 = b2[f];
  for (int c = 0; c < 256; c++) a2 = fmaf(h1[c], w2[c*256+f], a2);
  H[(size_t)r*256 + f] = eluf(a2);
}

// BN over 256 rows (single block); writes bf16 normalized
__global__ void bn_small(const float* __restrict__ H, const float* __restrict__ g, const float* __restrict__ be,
                         bf16* __restrict__ Xout){
  int f = threadIdx.x;
  float s = 0.f, s2 = 0.f;
  for (int r = 0; r < 256; r++){ float v = H[r*256+f]; s += v; s2 += v*v; }
  float m = s * (1.f/256.f), var = s2 * (1.f/256.f) - m*m;
  float sc = g[f] * rsqrtf(var + EPSV), sh = be[f] - m*sc;
  for (int r = 0; r < 256; r++) Xout[r*256+f] = __float2bfloat16(H[r*256+f]*sc + sh);
}

// ---------------- generic MFMA GEMM: Y = act(A @ W + b) ----------------
template<int K, int NCOLS, int ACT, bool OBF, int MT, bool STATS>
__global__ __launch_bounds__(256,4) void gemm_mfma(const bf16* __restrict__ A, const bf16* __restrict__ WT,
                                                   const float* __restrict__ bias, void* __restrict__ Y,
                                                   float* __restrict__ part){
  constexpr int NTW = NCOLS/64;           // n-tiles per wave
  int mb = blockIdx.x;
  int tid = threadIdx.x;
  int w = tid >> 6, l = tid & 63, l15 = l & 15, lq = l >> 4;
  f32x4 acc[MT/16][NTW];
  #pragma unroll
  for (int m = 0; m < MT/16; m++)
    #pragma unroll
    for (int nt = 0; nt < NTW; nt++) acc[m][nt] = (f32x4){0.f,0.f,0.f,0.f};
  const bf16* Ab = A + (size_t)mb*MT*K;
  int nw = w*(NCOLS/4);
  for (int s = 0; s < K/32; s++){
    int c0 = s*32 + lq*8;
    bf16x8 bfr[NTW];
    #pragma unroll
    for (int nt = 0; nt < NTW; nt++){
      int fcol = nw + nt*16 + l15;
      bfr[nt] = *reinterpret_cast<const bf16x8*>(WT + (size_t)fcol*K + c0);
    }
    #pragma unroll
    for (int m = 0; m < MT/16; m++){
      bf16x8 afr = *reinterpret_cast<const bf16x8*>(Ab + (size_t)(m*16 + l15)*K + c0);
      #pragma unroll
      for (int nt = 0; nt < NTW; nt++)
        acc[m][nt] = __builtin_amdgcn_mfma_f32_16x16x32_bf16(afr, bfr[nt], acc[m][nt], 0, 0, 0);
    }
  }
  #pragma unroll
  for (int nt = 0; nt < NTW; nt++){
    int fcol = nw + nt*16 + l15;
    float bv = bias[fcol];
    float cs = 0.f, cs2 = 0.f;
    #pragma unroll
    for (int m = 0; m < MT/16; m++){
      #pragma unroll
      for (int v = 0; v < 4; v++){
        int row = mb*MT + m*16 + lq*4 + v;
        float val = acc[m][nt][v] + bv;
        if (ACT == 1) val = fmaxf(val, 0.f);
        else if (ACT == 2) val = eluf(val);
        if (OBF) ((bf16*)Y)[(size_t)row*NCOLS + fcol] = __float2bfloat16(val);
        else     ((float*)Y)[(size_t)row*NCOLS + fcol] = val;
        if (STATS){ cs += val; cs2 += val*val; }
      }
    }
    if (STATS){
      cs  += __shfl_xor(cs, 16);  cs  += __shfl_xor(cs, 32);
      cs2 += __shfl_xor(cs2, 16); cs2 += __shfl_xor(cs2, 32);
      if (l < 16){ part[(size_t)mb*512 + fcol] = cs; part[(size_t)mb*512 + 256 + fcol] = cs2; }
    }
  }
}

// ---------------- edge combiners ----------------
__global__ void combine2(const bf16* __restrict__ SR, bf16* __restrict__ Y){
  int i = blockIdx.x*256 + threadIdx.x;   // 7936*32 chunks
  int row = i >> 5, c8 = (i & 31)*8;
  int b = row / NEDGE, e = row % NEDGE;
  int rc = e / 31, jj = e % 31;
  int sn = jj + (jj >= rc);
  bf16x8 s8 = *reinterpret_cast<const bf16x8*>(SR + (size_t)(b*NNODES + sn)*512 + c8);
  bf16x8 r8 = *reinterpret_cast<const bf16x8*>(SR + (size_t)(b*NNODES + rc)*512 + 256 + c8);
  bf16x8 o;
  #pragma unroll
  for (int k = 0; k < 8; k++){
    float v = bfu2f((unsigned short)s8[k]) + bfu2f((unsigned short)r8[k]);
    v = eluf(v);
    __hip_bfloat16 h = __float2bfloat16(v);
    o[k] = *reinterpret_cast<short*>(&h);
  }
  *reinterpret_cast<bf16x8*>(Y + (size_t)row*256 + c8) = o;
}

__global__ void combine4(const bf16* __restrict__ SR, const float* __restrict__ Z, bf16* __restrict__ Y){
  int i = blockIdx.x*256 + threadIdx.x;
  int row = i >> 5, c8 = (i & 31)*8;
  int b = row / NEDGE, e = row % NEDGE;
  int rc = e / 31, jj = e % 31;
  int sn = jj + (jj >= rc);
  bf16x8 s8 = *reinterpret_cast<const bf16x8*>(SR + (size_t)(b*NNODES + sn)*512 + c8);
  bf16x8 r8 = *reinterpret_cast<const bf16x8*>(SR + (size_t)(b*NNODES + rc)*512 + 256 + c8);
  const float* zp = Z + (size_t)row*256 + c8;
  float4 z0 = *reinterpret_cast<const float4*>(zp);
  float4 z1 = *reinterpret_cast<const float4*>(zp+4);
  float zz[8] = {z0.x,z0.y,z0.z,z0.w,z1.x,z1.y,z1.z,z1.w};
  bf16x8 o;
  #pragma unroll
  for (int k = 0; k < 8; k++){
    float v = bfu2f((unsigned short)s8[k]) + bfu2f((unsigned short)r8[k]) + zz[k];
    v = eluf(v);
    __hip_bfloat16 h = __float2bfloat16(v);
    o[k] = *reinterpret_cast<short*>(&h);
  }
  *reinterpret_cast<bf16x8*>(Y + (size_t)row*256 + c8) = o;
}

// ---------------- batchnorm finalize/apply ----------------
__global__ void bn_finalize(const float* __restrict__ part, int nb, const float* __restrict__ g,
                            const float* __restrict__ be, float* __restrict__ prm, float nrows){
  int f = threadIdx.x;
  float s = 0.f, s2 = 0.f;
  for (int i = 0; i < nb; i++){ s += part[(size_t)i*512+f]; s2 += part[(size_t)i*512+256+f]; }
  float m = s / nrows, var = s2 / nrows - m*m;
  float sc = g[f] * rsqrtf(var + EPSV);
  prm[f] = sc; prm[256+f] = be[f] - m*sc;
}
__global__ void bn_apply(const float* __restrict__ Y, const float* __restrict__ prm, bf16* __restrict__ X){
  int i = blockIdx.x*256 + threadIdx.x;    // 7936*32 chunks of 8
  int c8 = (i & 31)*8;
  const float* yp = Y + (size_t)i*8;
  float4 a0 = *reinterpret_cast<const float4*>(yp);
  float4 a1 = *reinterpret_cast<const float4*>(yp+4);
  float4 s0 = *reinterpret_cast<const float4*>(prm + c8);
  float4 s1 = *reinterpret_cast<const float4*>(prm + c8 + 4);
  float4 h0 = *reinterpret_cast<const float4*>(prm + 256 + c8);
  float4 h1 = *reinterpret_cast<const float4*>(prm + 256 + c8 + 4);
  float vals[8] = {a0.x*s0.x+h0.x, a0.y*s0.y+h0.y, a0.z*s0.z+h0.z, a0.w*s0.w+h0.w,
                   a1.x*s1.x+h1.x, a1.y*s1.y+h1.y, a1.z*s1.z+h1.z, a1.w*s1.w+h1.w};
  bf16x8 o;
  #pragma unroll
  for (int k = 0; k < 8; k++){
    __hip_bfloat16 h = __float2bfloat16(vals[k]);
    o[k] = *reinterpret_cast<short*>(&h);
  }
  *reinterpret_cast<bf16x8*>(X + (size_t)i*8) = o;
}

// ---------------- incoming = segment-sum over 31 edges / N ----------------
__global__ void seg_incoming(const bf16* __restrict__ X2, float* __restrict__ inc){
  int bn = blockIdx.x; int b = bn >> 5, n = bn & 31;
  int f = threadIdx.x;
  const bf16* p = X2 + (size_t)(b*NEDGE + n*31)*256 + f;
  float s = 0.f;
  for (int j = 0; j < 31; j++) s += __bfloat162float(p[j*256]);
  inc[bn*256 + f] = s * (1.f/32.f);
}

// ---------------- fc + softmax (prob out, rel_type to ws) ----------------
__global__ void fc_softmax(const bf16* __restrict__ X4, const float* __restrict__ fcw, const float* __restrict__ fcb,
                           const float* __restrict__ gumbel, float* __restrict__ prob_out, float* __restrict__ rt){
  int r = blockIdx.x*256 + threadIdx.x;
  if (r >= ROWS_E) return;
  float l0 = fcb[0], l1 = fcb[1], l2 = fcb[2], l3 = fcb[3];
  const bf16* xr = X4 + (size_t)r*256;
  for (int c = 0; c < 256; c += 8){
    uint4 u = *reinterpret_cast<const uint4*>(xr + c);
    unsigned uu[4] = {u.x, u.y, u.z, u.w};
    #pragma unroll
    for (int q = 0; q < 4; q++){
      float x0 = bfu2f((unsigned short)(uu[q] & 0xffff));
      float x1 = bfu2f((unsigned short)(uu[q] >> 16));
      int cc = c + 2*q;
      float4 w0 = *reinterpret_cast<const float4*>(fcw + cc*4);
      float4 w1 = *reinterpret_cast<const float4*>(fcw + (cc+1)*4);
      l0 += x0*w0.x + x1*w1.x; l1 += x0*w0.y + x1*w1.y;
      l2 += x0*w0.z + x1*w1.z; l3 += x0*w0.w + x1*w1.w;
    }
  }
  float mx = fmaxf(fmaxf(l0,l1), fmaxf(l2,l3));
  float e0 = __expf(l0-mx), e1 = __expf(l1-mx), e2 = __expf(l2-mx), e3 = __expf(l3-mx);
  float inv = 1.f / (e0+e1+e2+e3);
  prob_out[(size_t)r*4+0] = e0*inv; prob_out[(size_t)r*4+1] = e1*inv;
  prob_out[(size_t)r*4+2] = e2*inv; prob_out[(size_t)r*4+3] = e3*inv;
  float4 gv = *reinterpret_cast<const float4*>(gumbel + (size_t)r*4);
  float t0 = (l0+gv.x)*2.f, t1 = (l1+gv.y)*2.f, t2 = (l2+gv.z)*2.f, t3 = (l3+gv.w)*2.f;
  float mx2 = fmaxf(fmaxf(t0,t1), fmaxf(t2,t3));
  float f0 = __expf(t0-mx2), f1 = __expf(t1-mx2), f2 = __expf(t2-mx2), f3 = __expf(t3-mx2);
  float inv2 = 1.f / (f0+f1+f2+f3);
  rt[(size_t)r*4+0] = f0*inv2; rt[(size_t)r*4+1] = f1*inv2;
  rt[(size_t)r*4+2] = f2*inv2; rt[(size_t)r*4+3] = f3*inv2;
}

// ---------------- fused decoder message passing v7 ----------------
// 64-row blocks (2 receivers), 4 waves, acc[4][4]=64 AGPR, hA 32KB -> 4 waves/SIMD.
// Split-S register build: thread owns col-pair x 16-row-half -> only 17 S-pairs live.
// Pad rows (31,63) pre-zeroed once; MFMA path needs no masking.
__global__ __launch_bounds__(256,4) void decoder_msg(
    const float* __restrict__ data, const float* __restrict__ rt,
    const float* __restrict__ mw1, const float* __restrict__ mb1,
    const bf16* __restrict__ mw2T, const float* __restrict__ mb2,
    bf16* __restrict__ Aaug){
  __shared__ __align__(16) short hA[64*256];    // 32KB, xor-swizzled bf16
  __shared__ __align__(16) float xn[32][4];
  __shared__ __align__(16) float rts_s[64][4];
  __shared__ __align__(16) float aggl[2][256];
  int bx = blockIdx.x;
  int bt = bx >> 4, rg = bx & 15;
  int b = bt / TSTEPS, t = bt % TSTEPS;
  int n0 = rg * 2;
  int tid = threadIdx.x;
  int w = tid >> 6, l = tid & 63, l15 = l & 15, lq = l >> 4;

  if (tid < 32){
    *reinterpret_cast<float4*>(&xn[tid][0]) =
        *reinterpret_cast<const float4*>(data + ((size_t)(b*NNODES + tid)*TSTEPS + t)*4);
  } else if (tid >= 64 && tid < 128){
    int r = tid - 64;
    int n = n0 + (r >> 5), j = r & 31;
    float4 rv = make_float4(0.f,0.f,0.f,0.f);
    if (j < 31) rv = *reinterpret_cast<const float4*>(rt + ((size_t)(b*NEDGE + n*31 + j))*4);
    *reinterpret_cast<float4*>(&rts_s[r][0]) = rv;
  }
  for (int i = tid; i < 512; i += 256) ((float*)aggl)[i] = 0.f;
  // zero pad rows 31 and 63 of hA (128 words each); never rewritten
  {
    unsigned* hw = reinterpret_cast<unsigned*>(hA);
    hw[(tid < 128) ? (31*128 + tid) : (63*128 + (tid - 128))] = 0u;
  }
  __syncthreads();

  int c2 = tid & 127;      // col pair 2c2, 2c2+1
  int rh = tid >> 7;       // row-half: aj in [rh*16, rh*16+16)
  int xorbase = 4*c2;      // byte offset of col pair before swizzle

  for (int kk = 1; kk < 4; kk++){
    { // ---- phase 1: split-S register build of hA ----
      float2 a0 = *reinterpret_cast<const float2*>(mw1 + (size_t)(kk*8+0)*256 + 2*c2);
      float2 a1 = *reinterpret_cast<const float2*>(mw1 + (size_t)(kk*8+1)*256 + 2*c2);
      float2 a2 = *reinterpret_cast<const float2*>(mw1 + (size_t)(kk*8+2)*256 + 2*c2);
      float2 a3 = *reinterpret_cast<const float2*>(mw1 + (size_t)(kk*8+3)*256 + 2*c2);
      float2 a4 = *reinterpret_cast<const float2*>(mw1 + (size_t)(kk*8+4)*256 + 2*c2);
      float2 a5 = *reinterpret_cast<const float2*>(mw1 + (size_t)(kk*8+5)*256 + 2*c2);
      float2 a6 = *reinterpret_cast<const float2*>(mw1 + (size_t)(kk*8+6)*256 + 2*c2);
      float2 a7 = *reinterpret_cast<const float2*>(mw1 + (size_t)(kk*8+7)*256 + 2*c2);
      float2 bb = *reinterpret_cast<const float2*>(mb1 + kk*256 + 2*c2);
      float Sa[17], Sb[17];
      #pragma unroll
      for (int i = 0; i < 17; i++){
        int nd = rh*16 + i; if (nd > 31) nd = 31;   // i==16 unused when rh==1
        float4 x = *reinterpret_cast<float4*>(&xn[nd][0]);
        Sa[i] = fmaf(x.x,a0.x, fmaf(x.y,a1.x, fmaf(x.z,a2.x, fmaf(x.w,a3.x, bb.x))));
        Sb[i] = fmaf(x.x,a0.y, fmaf(x.y,a1.y, fmaf(x.z,a2.y, fmaf(x.w,a3.y, bb.y))));
      }
      float4 x0 = *reinterpret_cast<float4*>(&xn[n0][0]);
      float4 x1 = *reinterpret_cast<float4*>(&xn[n0+1][0]);
      float Ra0 = fmaf(x0.x,a4.x, fmaf(x0.y,a5.x, fmaf(x0.z,a6.x, x0.w*a7.x)));
      float Rb0 = fmaf(x0.x,a4.y, fmaf(x0.y,a5.y, fmaf(x0.z,a6.y, x0.w*a7.y)));
      float Ra1 = fmaf(x1.x,a4.x, fmaf(x1.y,a5.x, fmaf(x1.z,a6.x, x1.w*a7.x)));
      float Rb1 = fmaf(x1.x,a4.y, fmaf(x1.y,a5.y, fmaf(x1.z,a6.y, x1.w*a7.y)));
      char* hAb = reinterpret_cast<char*>(hA);
      #pragma unroll
      for (int ii = 0; ii < 16; ii++){
        int aj = rh*16 + ii;                // runtime-uniform per half
        if (aj < 31){
          { // receiver 0 (node n0), row r = aj
            bool sel = (aj >= n0);
            float sa = sel ? Sa[ii+1] : Sa[ii];
            float sb = sel ? Sb[ii+1] : Sb[ii];
            unsigned pk = cvt_pk_bf16(fmaxf(sa + Ra0, 0.f), fmaxf(sb + Rb0, 0.f));
            int r = aj;
            *reinterpret_cast<unsigned*>(hAb + r*512 + (xorbase ^ ((r & 7) << 4))) = pk;
          }
          { // receiver 1 (node n0+1), row r = 32 + aj
            bool sel = (aj >= n0+1);
            float sa = sel ? Sa[ii+1] : Sa[ii];
            float sb = sel ? Sb[ii+1] : Sb[ii];
            unsigned pk = cvt_pk_bf16(fmaxf(sa + Ra1, 0.f), fmaxf(sb + Rb1, 0.f));
            int r = 32 + aj;
            *reinterpret_cast<unsigned*>(hAb + r*512 + (xorbase ^ ((r & 7) << 4))) = pk;
          }
        }
      }
    }
    __syncthreads();

    // ---- phase 2: MFMA — wave owns 4 n-tiles (64 cols) x all 4 m-tiles ----
    f32x4 acc[4][4];
    #pragma unroll
    for (int m = 0; m < 4; m++)
      #pragma unroll
      for (int nt = 0; nt < 4; nt++) acc[m][nt] = (f32x4){0.f,0.f,0.f,0.f};
    const bf16* wk = mw2T + (size_t)kk*65536;
    for (int s = 0; s < 8; s++){
      int c0 = s*32 + lq*8;
      bf16x8 bfr[4];
      #pragma unroll
      for (int nt = 0; nt < 4; nt++){
        int fcol = w*64 + nt*16 + l15;
        bfr[nt] = *reinterpret_cast<const bf16x8*>(wk + (size_t)fcol*256 + c0);
      }
      #pragma unroll
      for (int m = 0; m < 4; m++){
        int rowm = m*16 + l15;
        int byteoff = rowm*512 + ((s*64 + lq*16) ^ ((rowm & 7) << 4));
        bf16x8 af = *reinterpret_cast<const bf16x8*>(reinterpret_cast<const char*>(hA) + byteoff);
        #pragma unroll
        for (int nt = 0; nt < 4; nt++)
          acc[m][nt] = __builtin_amdgcn_mfma_f32_16x16x32_bf16(af, bfr[nt], acc[m][nt], 0, 0, 0);
      }
    }
    // ---- epilogue: relu(+b2) * rel_type, column-reduce into per-receiver agg ----
    #pragma unroll
    for (int m = 0; m < 4; m++){
      int g = m >> 1;
      #pragma unroll
      for (int nt = 0; nt < 4; nt++){
        int fcol = w*64 + nt*16 + l15;
        float bv = mb2[kk*256 + fcol];
        float ssum = 0.f;
        #pragma unroll
        for (int v = 0; v < 4; v++){
          int rowa = m*16 + lq*4 + v;
          float msg = fmaxf(acc[m][nt][v] + bv, 0.f);
          ssum += msg * rts_s[rowa][kk];
        }
        ssum += __shfl_xor(ssum, 16);
        ssum += __shfl_xor(ssum, 32);
        if (lq == 0) aggl[g][fcol] += ssum;
      }
    }
    __syncthreads();
  }

  // write aug rows: [data(4) | agg(256) | pad(28)] bf16, K=288
  for (int i = tid; i < 2*288; i += 256){
    int g = i / 288, c = i % 288;
    float val;
    if (c < 4)        val = xn[n0+g][c];
    else if (c < 260) val = aggl[g][c-4];
    else              val = 0.f;
    Aaug[(size_t)(bt*NNODES + n0 + g)*288 + c] = __float2bfloat16(val);
  }
}

// ---------------- final: p3 = P2 @ ow3 + ob3 ; out = data + p3 (t<48) ----------------
__global__ void final_out(const bf16* __restrict__ P2, const float* __restrict__ ow3,
                          const float* __restrict__ ob3, const float* __restrict__ data,
                          float* __restrict__ out){
  int r = blockIdx.x*256 + threadIdx.x;
  if (r >= ROWS_OUT) return;
  int bt = r >> 5, n = r & 31;
  int b = bt / TSTEPS, t = bt % TSTEPS;
  float a0 = ob3[0], a1 = ob3[1], a2 = ob3[2], a3 = ob3[3];
  const bf16* pr = P2 + (size_t)r*256;
  for (int c = 0; c < 256; c += 8){
    uint4 u = *reinterpret_cast<const uint4*>(pr + c);
    unsigned uu[4] = {u.x, u.y, u.z, u.w};
    #pragma unroll
    for (int q = 0; q < 4; q++){
      float x0 = bfu2f((unsigned short)(uu[q] & 0xffff));
      float x1 = bfu2f((unsigned short)(uu[q] >> 16));
      int cc = c + 2*q;
      float4 w0 = *reinterpret_cast<const float4*>(ow3 + cc*4);
      float4 w1 = *reinterpret_cast<const float4*>(ow3 + (cc+1)*4);
      a0 += x0*w0.x + x1*w1.x; a1 += x0*w0.y + x1*w1.y;
      a2 += x0*w0.z + x1*w1.z; a3 += x0*w0.w + x1*w1.w;
    }
  }
  if (t < TSTEPS-1){
    float4 dv = *reinterpret_cast<const float4*>(data + ((size_t)(b*NNODES + n)*TSTEPS + t)*4);
    float4 o; o.x = dv.x + a0; o.y = dv.y + a1; o.z = dv.z + a2; o.w = dv.w + a3;
    *reinterpret_cast<float4*>(out + ((size_t)(b*NNODES + n)*(TSTEPS-1) + t)*4) = o;
  }
}

// ---------------- launcher ----------------
extern "C" void kernel_launch(void* const* d_in, const int* in_sizes, int n_in,
                              void* d_out, int out_size, void* d_ws, size_t ws_size,
                              hipStream_t stream){
  const float* data    = (const float*)d_in[0];
  const float* gumbel  = (const float*)d_in[1];
  const float* e1_w1=(const float*)d_in[4],  *e1_b1=(const float*)d_in[5],
             * e1_w2=(const float*)d_in[6],  *e1_b2=(const float*)d_in[7],
             * e1_g =(const float*)d_in[8],  *e1_be=(const float*)d_in[9];
  const float* e2_w1=(const float*)d_in[10], *e2_b1=(const float*)d_in[11],
             * e2_w2=(const float*)d_in[12], *e2_b2=(const float*)d_in[13],
             * e2_g =(const float*)d_in[14], *e2_be=(const float*)d_in[15];
  const float* e3_w1=(const float*)d_in[16], *e3_b1=(const float*)d_in[17],
             * e3_w2=(const float*)d_in[18], *e3_b2=(const float*)d_in[19],
             * e3_g =(const float*)d_in[20], *e3_be=(const float*)d_in[21];
  const float* e4_w1=(const float*)d_in[22], *e4_b1=(const float*)d_in[23],
             * e4_w2=(const float*)d_in[24], *e4_b2=(const float*)d_in[25],
             * e4_g =(const float*)d_in[26], *e4_be=(const float*)d_in[27];
  const float* fc_w=(const float*)d_in[28], *fc_b=(const float*)d_in[29];
  const float* mw1=(const float*)d_in[30], *mb1=(const float*)d_in[31];
  const float* mw2=(const float*)d_in[32], *mb2=(const float*)d_in[33];
  const float* ow1=(const float*)d_in[34], *ob1=(const float*)d_in[35];
  const float* ow2=(const float*)d_in[36], *ob2=(const float*)d_in[37];
  const float* ow3=(const float*)d_in[38], *ob3=(const float*)d_in[39];

  char* ws = (char*)d_ws;
  size_t off = 0;
  auto alloc = [&](size_t bytes)->void*{ void* p = ws + off; off = (off + bytes + 255) & ~(size_t)255; return p; };
  bf16* W2ABT= (bf16*)alloc((size_t)131072*2);
  bf16* W2BT = (bf16*)alloc((size_t)65536*2);
  bf16* W4ABT= (bf16*)alloc((size_t)131072*2);
  bf16* W4CT = (bf16*)alloc((size_t)65536*2);
  bf16* W4BT = (bf16*)alloc((size_t)65536*2);
  bf16* MW2T = (bf16*)alloc((size_t)262144*2);
  bf16* OW1T = (bf16*)alloc((size_t)73728*2);
  bf16* OW2T = (bf16*)alloc((size_t)65536*2);
  float* BIAS2=(float*)alloc((size_t)512*4);
  float* BIAS4=(float*)alloc((size_t)512*4);
  float* ZEROB=(float*)alloc((size_t)256*4);
  bf16* X1   = (bf16*)alloc((size_t)65536*2);
  float* HS  = (float*)alloc((size_t)65536*4);
  bf16* X3   = (bf16*)alloc((size_t)65536*2);
  bf16* SR2  = (bf16*)alloc((size_t)131072*2);
  bf16* SR4  = (bf16*)alloc((size_t)131072*2);
  float* Z4  = (float*)alloc((size_t)7936*256*4);
  bf16* YBF  = (bf16*)alloc((size_t)12544*256*2);
  float* YF32= (float*)alloc((size_t)7936*256*4);
  bf16* X2   = (bf16*)alloc((size_t)7936*256*2);
  bf16* X4   = (bf16*)alloc((size_t)7936*256*2);
  bf16* P2   = (bf16*)alloc((size_t)12544*256*2);
  float* INC = (float*)alloc((size_t)65536*4);
  float* RT  = (float*)alloc((size_t)7936*4*4);
  float* PART= (float*)alloc((size_t)248*512*4);
  float* PRM = (float*)alloc((size_t)512*4);
  bf16* AAUG = (bf16*)alloc((size_t)12544*288*2);

  float* out = (float*)d_out;
  float* prob_out = out + 49152;

  prep_weights<<<3365,256,0,stream>>>(e2_w1,e2_w2,e4_w1,e4_w2,mw2,ow1,ow2,e2_b1,e4_b1,
                                      W2ABT,W2BT,W4ABT,W4CT,W4BT,MW2T,OW1T,OW2T,BIAS2,BIAS4,ZEROB);
  small_mlp<196><<<256,256,0,stream>>>(data, e1_w1,e1_b1,e1_w2,e1_b2, HS);
  bn_small<<<1,256,0,stream>>>(HS, e1_g, e1_be, X1);
  gemm_mfma<256,512,0,true,32,false><<<8,256,0,stream>>>(X1, W2ABT, BIAS2, SR2, nullptr);
  combine2<<<992,256,0,stream>>>(SR2, YBF);
  gemm_mfma<256,256,2,false,32,true><<<248,256,0,stream>>>(YBF, W2BT, e2_b2, YF32, PART);
  bn_finalize<<<1,256,0,stream>>>(PART, 248, e2_g, e2_be, PRM, 7936.f);
  bn_apply<<<992,256,0,stream>>>(YF32, PRM, X2);
  seg_incoming<<<256,256,0,stream>>>(X2, INC);
  small_mlp<256><<<256,256,0,stream>>>(INC, e3_w1,e3_b1,e3_w2,e3_b2, HS);
  bn_small<<<1,256,0,stream>>>(HS, e3_g, e3_be, X3);
  gemm_mfma<256,512,0,true,32,false><<<8,256,0,stream>>>(X3, W4ABT, BIAS4, SR4, nullptr);
  gemm_mfma<256,256,0,false,32,false><<<248,256,0,stream>>>(X2, W4CT, ZEROB, Z4, nullptr);
  combine4<<<992,256,0,stream>>>(SR4, Z4, YBF);
  gemm_mfma<256,256,2,false,32,true><<<248,256,0,stream>>>(YBF, W4BT, e4_b2, YF32, PART);
  bn_finalize<<<1,256,0,stream>>>(PART, 248, e4_g, e4_be, PRM, 7936.f);
  bn_apply<<<992,256,0,stream>>>(YF32, PRM, X4);
  fc_softmax<<<31,256,0,stream>>>(X4, fc_w, fc_b, gumbel, prob_out, RT);
  decoder_msg<<<6272,256,0,stream>>>(data, RT, mw1, mb1, MW2T, mb2, AAUG);
  gemm_mfma<288,256,1,true,32,false><<<392,256,0,stream>>>(AAUG, OW1T, ob1, YBF, nullptr);
  gemm_mfma<256,256,1,true,32,false><<<392,256,0,stream>>>(YBF, OW2T, ob2, P2, nullptr);
  final_out<<<49,256,0,stream>>>(P2, ow3, ob3, data, out);
}

// Round 6
// 800.184 us; speedup vs baseline: 1.0498x; 1.0498x over previous
//
#include <hip/hip_runtime.h>
#include <hip/hip_bf16.h>

#define NNODES 32
#define TSTEPS 49
#define NEDGE  992
#define ROWS_E 7936     // B*E
#define ROWS_OUT 12544  // B*T*N
#define EPSV 1e-5f

typedef __hip_bfloat16 bf16;
typedef __attribute__((ext_vector_type(8))) short bf16x8;
typedef __attribute__((ext_vector_type(4))) float f32x4;

__device__ inline float eluf(float x){ return x > 0.f ? x : (__expf(x) - 1.f); }
__device__ inline float bfu2f(unsigned short u){ unsigned v = ((unsigned)u) << 16; return *reinterpret_cast<float*>(&v); }
__device__ inline float lo_f(unsigned u){ unsigned v = u << 16; return *reinterpret_cast<float*>(&v); }
__device__ inline float hi_f(unsigned u){ unsigned v = u & 0xffff0000u; return *reinterpret_cast<float*>(&v); }
__device__ inline unsigned cvt_pk_bf16(float lo, float hi){
  unsigned r;
  asm("v_cvt_pk_bf16_f32 %0, %1, %2" : "=v"(r) : "v"(lo), "v"(hi));
  return r;
}

// ---------------- weight prep: transpose + bf16 convert + bias builds ----------------
__global__ void prep_weights(const float* e2w1, const float* e2w2, const float* e4w1, const float* e4w2,
                             const float* mw2, const float* ow1, const float* ow2,
                             const float* e2b1, const float* e4b1,
                             bf16* w2abT, bf16* w2bT, bf16* w4abT, bf16* w4cT, bf16* w4bT,
                             bf16* mw2T, bf16* ow1T, bf16* ow2T,
                             float* bias2, float* bias4, float* zerob){
  int i = blockIdx.x*256 + threadIdx.x;
  if (i < 131072){ int n=i>>8, c=i&255;
    w2abT[i] = __float2bfloat16(n<256 ? e2w1[c*256+n] : e2w1[(256+c)*256 + (n-256)]); return;} i-=131072;
  if (i < 65536){ int n=i>>8,c=i&255; w2bT[i]=__float2bfloat16(e2w2[c*256+n]); return;} i-=65536;
  if (i < 131072){ int n=i>>8,c=i&255;
    w4abT[i]=__float2bfloat16(n<256 ? e4w1[c*256+n] : e4w1[(256+c)*256+(n-256)]); return;} i-=131072;
  if (i < 65536){ int n=i>>8,c=i&255; w4cT[i]=__float2bfloat16(e4w1[(512+c)*256+n]); return;} i-=65536;
  if (i < 65536){ int n=i>>8,c=i&255; w4bT[i]=__float2bfloat16(e4w2[c*256+n]); return;} i-=65536;
  if (i < 262144){ int k=i>>16, r=i&65535; int n=r>>8,c=r&255;
    mw2T[i]=__float2bfloat16(mw2[(k*256+c)*256+n]); return;} i-=262144;
  if (i < 73728){ int n=i/288, c=i%288;
    ow1T[i]= (c<260)?__float2bfloat16(ow1[c*256+n]):__float2bfloat16(0.f); return;} i-=73728;
  if (i < 65536){ int n=i>>8,c=i&255; ow2T[i]=__float2bfloat16(ow2[c*256+n]); return;} i-=65536;
  if (i < 512){ bias2[i] = (i<256)?e2b1[i]:0.f; return;} i-=512;
  if (i < 512){ bias4[i] = (i<256)?e4b1[i]:0.f; return;} i-=512;
  if (i < 256){ zerob[i]=0.f; return; }
}

// ---------------- small 2-layer ELU MLP (256 rows), fp32 VALU ----------------
template<int KIN>
__global__ void small_mlp(const float* __restrict__ X, const float* __restrict__ w1, const float* __restrict__ b1,
                          const float* __restrict__ w2, const float* __restrict__ b2, float* __restrict__ H){
  __shared__ float xs[KIN];
  __shared__ float h1[256];
  int r = blockIdx.x, f = threadIdx.x;
  for (int c = f; c < KIN; c += 256) xs[c] = X[(size_t)r*KIN + c];
  __syncthreads();
  float acc = b1[f];
  for (int c = 0; c < KIN; c++) acc = fmaf(xs[c], w1[c*256+f], acc);
  h1[f] = eluf(acc);
  __syncthreads();
  float a2 = b2[f];
  for (int c = 0; c < 256; c++) a2 = fmaf(h1[c], w2[c*256+f], a2);
  H[(size_t)r*256 + f] = eluf(a2);
}

// BN over 256 rows (single block); writes bf16 normalized
__global__ void bn_small(const float* __restrict__ H, const float* __restrict__ g, const float* __restrict__ be,
                         bf16* __restrict__ Xout){
  int f = threadIdx.x;
  float s = 0.f, s2 = 0.f;
  for (int r = 0; r < 256; r++){ float v = H[r*256+f]; s += v; s2 += v*v; }
  float m = s * (1.f/256.f), var = s2 * (1.f/256.f) - m*m;
  float sc = g[f] * rsqrtf(var + EPSV), sh = be[f] - m*sc;
  for (int r = 0; r < 256; r++) Xout[r*256+f] = __float2bfloat16(H[r*256+f]*sc + sh);
}

// ---------------- generic MFMA GEMM: Y = act(A @ W + b) ----------------
template<int K, int NCOLS, int ACT, bool OBF, int MT, bool STATS>
__global__ __launch_bounds__(256,4) void gemm_mfma(const bf16* __restrict__ A, const bf16* __restrict__ WT,
                                                   const float* __restrict__ bias, void* __restrict__ Y,
                                                   float* __restrict__ part){
  constexpr int NTW = NCOLS/64;           // n-tiles per wave
  int mb = blockIdx.x;
  int tid = threadIdx.x;
  int w = tid >> 6, l = tid & 63, l15 = l & 15, lq = l >> 4;
  f32x4 acc[MT/16][NTW];
  #pragma unroll
  for (int m = 0; m < MT/16; m++)
    #pragma unroll
    for (int nt = 0; nt < NTW; nt++) acc[m][nt] = (f32x4){0.f,0.f,0.f,0.f};
  const bf16* Ab = A + (size_t)mb*MT*K;
  int nw = w*(NCOLS/4);
  for (int s = 0; s < K/32; s++){
    int c0 = s*32 + lq*8;
    bf16x8 bfr[NTW];
    #pragma unroll
    for (int nt = 0; nt < NTW; nt++){
      int fcol = nw + nt*16 + l15;
      bfr[nt] = *reinterpret_cast<const bf16x8*>(WT + (size_t)fcol*K + c0);
    }
    #pragma unroll
    for (int m = 0; m < MT/16; m++){
      bf16x8 afr = *reinterpret_cast<const bf16x8*>(Ab + (size_t)(m*16 + l15)*K + c0);
      #pragma unroll
      for (int nt = 0; nt < NTW; nt++)
        acc[m][nt] = __builtin_amdgcn_mfma_f32_16x16x32_bf16(afr, bfr[nt], acc[m][nt], 0, 0, 0);
    }
  }
  #pragma unroll
  for (int nt = 0; nt < NTW; nt++){
    int fcol = nw + nt*16 + l15;
    float bv = bias[fcol];
    float cs = 0.f, cs2 = 0.f;
    #pragma unroll
    for (int m = 0; m < MT/16; m++){
      #pragma unroll
      for (int v = 0; v < 4; v++){
        int row = mb*MT + m*16 + lq*4 + v;
        float val = acc[m][nt][v] + bv;
        if (ACT == 1) val = fmaxf(val, 0.f);
        else if (ACT == 2) val = eluf(val);
        if (OBF) ((bf16*)Y)[(size_t)row*NCOLS + fcol] = __float2bfloat16(val);
        else     ((float*)Y)[(size_t)row*NCOLS + fcol] = val;
        if (STATS){ cs += val; cs2 += val*val; }
      }
    }
    if (STATS){
      cs  += __shfl_xor(cs, 16);  cs  += __shfl_xor(cs, 32);
      cs2 += __shfl_xor(cs2, 16); cs2 += __shfl_xor(cs2, 32);
      if (l < 16){ part[(size_t)mb*512 + fcol] = cs; part[(size_t)mb*512 + 256 + fcol] = cs2; }
    }
  }
}

// ---------------- edge combiners ----------------
__global__ void combine2(const bf16* __restrict__ SR, bf16* __restrict__ Y){
  int i = blockIdx.x*256 + threadIdx.x;   // 7936*32 chunks
  int row = i >> 5, c8 = (i & 31)*8;
  int b = row / NEDGE, e = row % NEDGE;
  int rc = e / 31, jj = e % 31;
  int sn = jj + (jj >= rc);
  bf16x8 s8 = *reinterpret_cast<const bf16x8*>(SR + (size_t)(b*NNODES + sn)*512 + c8);
  bf16x8 r8 = *reinterpret_cast<const bf16x8*>(SR + (size_t)(b*NNODES + rc)*512 + 256 + c8);
  bf16x8 o;
  #pragma unroll
  for (int k = 0; k < 8; k++){
    float v = bfu2f((unsigned short)s8[k]) + bfu2f((unsigned short)r8[k]);
    v = eluf(v);
    __hip_bfloat16 h = __float2bfloat16(v);
    o[k] = *reinterpret_cast<short*>(&h);
  }
  *reinterpret_cast<bf16x8*>(Y + (size_t)row*256 + c8) = o;
}

__global__ void combine4(const bf16* __restrict__ SR, const float* __restrict__ Z, bf16* __restrict__ Y){
  int i = blockIdx.x*256 + threadIdx.x;
  int row = i >> 5, c8 = (i & 31)*8;
  int b = row / NEDGE, e = row % NEDGE;
  int rc = e / 31, jj = e % 31;
  int sn = jj + (jj >= rc);
  bf16x8 s8 = *reinterpret_cast<const bf16x8*>(SR + (size_t)(b*NNODES + sn)*512 + c8);
  bf16x8 r8 = *reinterpret_cast<const bf16x8*>(SR + (size_t)(b*NNODES + rc)*512 + 256 + c8);
  const float* zp = Z + (size_t)row*256 + c8;
  float4 z0 = *reinterpret_cast<const float4*>(zp);
  float4 z1 = *reinterpret_cast<const float4*>(zp+4);
  float zz[8] = {z0.x,z0.y,z0.z,z0.w,z1.x,z1.y,z1.z,z1.w};
  bf16x8 o;
  #pragma unroll
  for (int k = 0; k < 8; k++){
    float v = bfu2f((unsigned short)s8[k]) + bfu2f((unsigned short)r8[k]) + zz[k];
    v = eluf(v);
    __hip_bfloat16 h = __float2bfloat16(v);
    o[k] = *reinterpret_cast<short*>(&h);
  }
  *reinterpret_cast<bf16x8*>(Y + (size_t)row*256 + c8) = o;
}

// ---------------- batchnorm finalize/apply ----------------
__global__ void bn_finalize(const float* __restrict__ part, int nb, const float* __restrict__ g,
                            const float* __restrict__ be, float* __restrict__ prm, float nrows){
  int f = threadIdx.x;
  float s = 0.f, s2 = 0.f;
  for (int i = 0; i < nb; i++){ s += part[(size_t)i*512+f]; s2 += part[(size_t)i*512+256+f]; }
  float m = s / nrows, var = s2 / nrows - m*m;
  float sc = g[f] * rsqrtf(var + EPSV);
  prm[f] = sc; prm[256+f] = be[f] - m*sc;
}
__global__ void bn_apply(const float* __restrict__ Y, const float* __restrict__ prm, bf16* __restrict__ X){
  int i = blockIdx.x*256 + threadIdx.x;    // 7936*32 chunks of 8
  int c8 = (i & 31)*8;
  const float* yp = Y + (size_t)i*8;
  float4 a0 = *reinterpret_cast<const float4*>(yp);
  float4 a1 = *reinterpret_cast<const float4*>(yp+4);
  float4 s0 = *reinterpret_cast<const float4*>(prm + c8);
  float4 s1 = *reinterpret_cast<const float4*>(prm + c8 + 4);
  float4 h0 = *reinterpret_cast<const float4*>(prm + 256 + c8);
  float4 h1 = *reinterpret_cast<const float4*>(prm + 256 + c8 + 4);
  float vals[8] = {a0.x*s0.x+h0.x, a0.y*s0.y+h0.y, a0.z*s0.z+h0.z, a0.w*s0.w+h0.w,
                   a1.x*s1.x+h1.x, a1.y*s1.y+h1.y, a1.z*s1.z+h1.z, a1.w*s1.w+h1.w};
  bf16x8 o;
  #pragma unroll
  for (int k = 0; k < 8; k++){
    __hip_bfloat16 h = __float2bfloat16(vals[k]);
    o[k] = *reinterpret_cast<short*>(&h);
  }
  *reinterpret_cast<bf16x8*>(X + (size_t)i*8) = o;
}

// ---------------- incoming = segment-sum over 31 edges / N ----------------
__global__ void seg_incoming(const bf16* __restrict__ X2, float* __restrict__ inc){
  int bn = blockIdx.x; int b = bn >> 5, n = bn & 31;
  int f = threadIdx.x;
  const bf16* p = X2 + (size_t)(b*NEDGE + n*31)*256 + f;
  float s = 0.f;
  for (int j = 0; j < 31; j++) s += __bfloat162float(p[j*256]);
  inc[bn*256 + f] = s * (1.f/32.f);
}

// ---------------- fc + softmax (prob out, rel_type to ws) ----------------
__global__ void fc_softmax(const bf16* __restrict__ X4, const float* __restrict__ fcw, const float* __restrict__ fcb,
                           const float* __restrict__ gumbel, float* __restrict__ prob_out, float* __restrict__ rt){
  int r = blockIdx.x*256 + threadIdx.x;
  if (r >= ROWS_E) return;
  float l0 = fcb[0], l1 = fcb[1], l2 = fcb[2], l3 = fcb[3];
  const bf16* xr = X4 + (size_t)r*256;
  for (int c = 0; c < 256; c += 8){
    uint4 u = *reinterpret_cast<const uint4*>(xr + c);
    unsigned uu[4] = {u.x, u.y, u.z, u.w};
    #pragma unroll
    for (int q = 0; q < 4; q++){
      float x0 = bfu2f((unsigned short)(uu[q] & 0xffff));
      float x1 = bfu2f((unsigned short)(uu[q] >> 16));
      int cc = c + 2*q;
      float4 w0 = *reinterpret_cast<const float4*>(fcw + cc*4);
      float4 w1 = *reinterpret_cast<const float4*>(fcw + (cc+1)*4);
      l0 += x0*w0.x + x1*w1.x; l1 += x0*w0.y + x1*w1.y;
      l2 += x0*w0.z + x1*w1.z; l3 += x0*w0.w + x1*w1.w;
    }
  }
  float mx = fmaxf(fmaxf(l0,l1), fmaxf(l2,l3));
  float e0 = __expf(l0-mx), e1 = __expf(l1-mx), e2 = __expf(l2-mx), e3 = __expf(l3-mx);
  float inv = 1.f / (e0+e1+e2+e3);
  prob_out[(size_t)r*4+0] = e0*inv; prob_out[(size_t)r*4+1] = e1*inv;
  prob_out[(size_t)r*4+2] = e2*inv; prob_out[(size_t)r*4+3] = e3*inv;
  float4 gv = *reinterpret_cast<const float4*>(gumbel + (size_t)r*4);
  float t0 = (l0+gv.x)*2.f, t1 = (l1+gv.y)*2.f, t2 = (l2+gv.z)*2.f, t3 = (l3+gv.w)*2.f;
  float mx2 = fmaxf(fmaxf(t0,t1), fmaxf(t2,t3));
  float f0 = __expf(t0-mx2), f1 = __expf(t1-mx2), f2 = __expf(t2-mx2), f3 = __expf(t3-mx2);
  float inv2 = 1.f / (f0+f1+f2+f3);
  rt[(size_t)r*4+0] = f0*inv2; rt[(size_t)r*4+1] = f1*inv2;
  rt[(size_t)r*4+2] = f2*inv2; rt[(size_t)r*4+3] = f3*inv2;
}

// ---------------- fused decoder message passing v8 ----------------
// R5 geometry (64-row blocks, 4 waves, acc[4][4], wave-owns-4-cols, swizzled hA)
// but S/R staged in LDS (not registers) -> no scratch spill.
// Phase 1a: thread owns col, builds S[32]/R[2] (4 FMA each). Phase 1b: thread owns
// col-pair x row-half, assembles hA = relu(S[snd]+R[recv]) via conflict-free LDS reads.
__global__ __launch_bounds__(256,4) void decoder_msg(
    const float* __restrict__ data, const float* __restrict__ rt,
    const float* __restrict__ mw1, const float* __restrict__ mb1,
    const bf16* __restrict__ mw2T, const float* __restrict__ mb2,
    bf16* __restrict__ Aaug){
  __shared__ __align__(16) short hA[64*256];    // 32KB, xor-swizzled
  __shared__ __align__(16) short Ssw[32*256];   // 16KB, xor-swizzled by node
  __shared__ __align__(16) short Rsw[2*256];    // 1KB
  __shared__ __align__(16) float xn[32][4];
  __shared__ __align__(16) float rts_s[64][4];
  __shared__ __align__(16) float aggl[2][256];
  int bx = blockIdx.x;
  int bt = bx >> 4, rg = bx & 15;
  int b = bt / TSTEPS, t = bt % TSTEPS;
  int n0 = rg * 2;
  int tid = threadIdx.x;
  int w = tid >> 6, l = tid & 63, l15 = l & 15, lq = l >> 4;

  if (tid < 32){
    *reinterpret_cast<float4*>(&xn[tid][0]) =
        *reinterpret_cast<const float4*>(data + ((size_t)(b*NNODES + tid)*TSTEPS + t)*4);
  } else if (tid >= 64 && tid < 128){
    int r = tid - 64;
    int n = n0 + (r >> 5), j = r & 31;
    float4 rv = make_float4(0.f,0.f,0.f,0.f);
    if (j < 31) rv = *reinterpret_cast<const float4*>(rt + ((size_t)(b*NEDGE + n*31 + j))*4);
    *reinterpret_cast<float4*>(&rts_s[r][0]) = rv;
  }
  for (int i = tid; i < 512; i += 256) ((float*)aggl)[i] = 0.f;
  // zero pad rows 31 and 63 of hA; never rewritten
  {
    unsigned* hw = reinterpret_cast<unsigned*>(hA);
    hw[(tid < 128) ? (31*128 + tid) : (63*128 + (tid - 128))] = 0u;
  }
  __syncthreads();

  int c2 = tid & 127;      // col pair 2c2, 2c2+1 (phase 1b)
  int rh = tid >> 7;       // row-half (phase 1b)

  for (int kk = 1; kk < 4; kk++){
    { // ---- phase 1a: S (32 nodes) + R (2 receivers) -> LDS; thread owns col c = tid
      float w0 = mw1[(size_t)(kk*8+0)*256 + tid];
      float w1 = mw1[(size_t)(kk*8+1)*256 + tid];
      float w2 = mw1[(size_t)(kk*8+2)*256 + tid];
      float w3 = mw1[(size_t)(kk*8+3)*256 + tid];
      float w4 = mw1[(size_t)(kk*8+4)*256 + tid];
      float w5 = mw1[(size_t)(kk*8+5)*256 + tid];
      float w6 = mw1[(size_t)(kk*8+6)*256 + tid];
      float w7 = mw1[(size_t)(kk*8+7)*256 + tid];
      float bs = mb1[kk*256 + tid];
      char* Sb = reinterpret_cast<char*>(Ssw);
      #pragma unroll 8
      for (int nd = 0; nd < 32; nd++){
        float4 x = *reinterpret_cast<float4*>(&xn[nd][0]);
        float sv = fmaf(x.x,w0, fmaf(x.y,w1, fmaf(x.z,w2, fmaf(x.w,w3, bs))));
        __hip_bfloat16 h = __float2bfloat16(sv);
        *reinterpret_cast<short*>(Sb + nd*512 + ((2*tid) ^ ((nd&7)<<4))) = *reinterpret_cast<short*>(&h);
      }
      float4 x0 = *reinterpret_cast<float4*>(&xn[n0][0]);
      float4 x1 = *reinterpret_cast<float4*>(&xn[n0+1][0]);
      float rv0 = fmaf(x0.x,w4, fmaf(x0.y,w5, fmaf(x0.z,w6, x0.w*w7)));
      float rv1 = fmaf(x1.x,w4, fmaf(x1.y,w5, fmaf(x1.z,w6, x1.w*w7)));
      __hip_bfloat16 h0 = __float2bfloat16(rv0);
      __hip_bfloat16 h1 = __float2bfloat16(rv1);
      Rsw[tid] = *reinterpret_cast<short*>(&h0);
      Rsw[256 + tid] = *reinterpret_cast<short*>(&h1);
    }
    __syncthreads();

    { // ---- phase 1b: hA = relu(S[snd] + R[recv]), swizzled writes ----
      unsigned r0 = *reinterpret_cast<unsigned*>(reinterpret_cast<char*>(Rsw) + 4*c2);
      unsigned r1 = *reinterpret_cast<unsigned*>(reinterpret_cast<char*>(Rsw) + 512 + 4*c2);
      float R0lo = lo_f(r0), R0hi = hi_f(r0);
      float R1lo = lo_f(r1), R1hi = hi_f(r1);
      const char* Sb = reinterpret_cast<const char*>(Ssw);
      char* hAb = reinterpret_cast<char*>(hA);
      #pragma unroll
      for (int ii = 0; ii < 16; ii++){
        int aj = rh*16 + ii;                 // wave-uniform
        if (aj < 31){
          { // receiver 0 (node n0), row aj
            int s0 = aj + (aj >= n0);
            unsigned su = *reinterpret_cast<const unsigned*>(Sb + s0*512 + ((4*c2) ^ ((s0&7)<<4)));
            unsigned pk = cvt_pk_bf16(fmaxf(lo_f(su)+R0lo, 0.f), fmaxf(hi_f(su)+R0hi, 0.f));
            *reinterpret_cast<unsigned*>(hAb + aj*512 + ((4*c2) ^ ((aj&7)<<4))) = pk;
          }
          { // receiver 1 (node n0+1), row 32+aj
            int s1 = aj + (aj >= n0+1);
            unsigned su = *reinterpret_cast<const unsigned*>(Sb + s1*512 + ((4*c2) ^ ((s1&7)<<4)));
            unsigned pk = cvt_pk_bf16(fmaxf(lo_f(su)+R1lo, 0.f), fmaxf(hi_f(su)+R1hi, 0.f));
            int r = 32 + aj;
            *reinterpret_cast<unsigned*>(hAb + r*512 + ((4*c2) ^ ((r&7)<<4))) = pk;
          }
        }
      }
    }
    __syncthreads();

    // ---- phase 2: MFMA — wave owns 4 n-tiles (64 cols) x all 4 m-tiles ----
    f32x4 acc[4][4];
    #pragma unroll
    for (int m = 0; m < 4; m++)
      #pragma unroll
      for (int nt = 0; nt < 4; nt++) acc[m][nt] = (f32x4){0.f,0.f,0.f,0.f};
    const bf16* wk = mw2T + (size_t)kk*65536;
    for (int s = 0; s < 8; s++){
      int c0 = s*32 + lq*8;
      bf16x8 bfr[4];
      #pragma unroll
      for (int nt = 0; nt < 4; nt++){
        int fcol = w*64 + nt*16 + l15;
        bfr[nt] = *reinterpret_cast<const bf16x8*>(wk + (size_t)fcol*256 + c0);
      }
      #pragma unroll
      for (int m = 0; m < 4; m++){
        int rowm = m*16 + l15;
        int byteoff = rowm*512 + ((s*64 + lq*16) ^ ((rowm & 7) << 4));
        bf16x8 af = *reinterpret_cast<const bf16x8*>(reinterpret_cast<const char*>(hA) + byteoff);
        #pragma unroll
        for (int nt = 0; nt < 4; nt++)
          acc[m][nt] = __builtin_amdgcn_mfma_f32_16x16x32_bf16(af, bfr[nt], acc[m][nt], 0, 0, 0);
      }
    }
    // ---- epilogue: relu(+b2) * rel_type, column-reduce into per-receiver agg ----
    #pragma unroll
    for (int m = 0; m < 4; m++){
      int g = m >> 1;
      #pragma unroll
      for (int nt = 0; nt < 4; nt++){
        int fcol = w*64 + nt*16 + l15;
        float bv = mb2[kk*256 + fcol];
        float ssum = 0.f;
        #pragma unroll
        for (int v = 0; v < 4; v++){
          int rowa = m*16 + lq*4 + v;
          float msg = fmaxf(acc[m][nt][v] + bv, 0.f);
          ssum += msg * rts_s[rowa][kk];
        }
        ssum += __shfl_xor(ssum, 16);
        ssum += __shfl_xor(ssum, 32);
        if (lq == 0) aggl[g][fcol] += ssum;
      }
    }
    __syncthreads();
  }

  // write aug rows: [data(4) | agg(256) | pad(28)] bf16, K=288
  for (int i = tid; i < 2*288; i += 256){
    int g = i / 288, c = i % 288;
    float val;
    if (c < 4)        val = xn[n0+g][c];
    else if (c < 260) val = aggl[g][c-4];
    else              val = 0.f;
    Aaug[(size_t)(bt*NNODES + n0 + g)*288 + c] = __float2bfloat16(val);
  }
}

// ---------------- final: p3 = P2 @ ow3 + ob3 ; out = data + p3 (t<48) ----------------
__global__ void final_out(const bf16* __restrict__ P2, const float* __restrict__ ow3,
                          const float* __restrict__ ob3, const float* __restrict__ data,
                          float* __restrict__ out){
  int r = blockIdx.x*256 + threadIdx.x;
  if (r >= ROWS_OUT) return;
  int bt = r >> 5, n = r & 31;
  int b = bt / TSTEPS, t = bt % TSTEPS;
  float a0 = ob3[0], a1 = ob3[1], a2 = ob3[2], a3 = ob3[3];
  const bf16* pr = P2 + (size_t)r*256;
  for (int c = 0; c < 256; c += 8){
    uint4 u = *reinterpret_cast<const uint4*>(pr + c);
    unsigned uu[4] = {u.x, u.y, u.z, u.w};
    #pragma unroll
    for (int q = 0; q < 4; q++){
      float x0 = bfu2f((unsigned short)(uu[q] & 0xffff));
      float x1 = bfu2f((unsigned short)(uu[q] >> 16));
      int cc = c + 2*q;
      float4 w0 = *reinterpret_cast<const float4*>(ow3 + cc*4);
      float4 w1 = *reinterpret_cast<const float4*>(ow3 + (cc+1)*4);
      a0 += x0*w0.x + x1*w1.x; a1 += x0*w0.y + x1*w1.y;
      a2 += x0*w0.z + x1*w1.z; a3 += x0*w0.w + x1*w1.w;
    }
  }
  if (t < TSTEPS-1){
    float4 dv = *reinterpret_cast<const float4*>(data + ((size_t)(b*NNODES + n)*TSTEPS + t)*4);
    float4 o; o.x = dv.x + a0; o.y = dv.y + a1; o.z = dv.z + a2; o.w = dv.w + a3;
    *reinterpret_cast<float4*>(out + ((size_t)(b*NNODES + n)*(TSTEPS-1) + t)*4) = o;
  }
}

// ---------------- launcher ----------------
extern "C" void kernel_launch(void* const* d_in, const int* in_sizes, int n_in,
                              void* d_out, int out_size, void* d_ws, size_t ws_size,
                              hipStream_t stream){
  const float* data    = (const float*)d_in[0];
  const float* gumbel  = (const float*)d_in[1];
  const float* e1_w1=(const float*)d_in[4],  *e1_b1=(const float*)d_in[5],
             * e1_w2=(const float*)d_in[6],  *e1_b2=(const float*)d_in[7],
             * e1_g =(const float*)d_in[8],  *e1_be=(const float*)d_in[9];
  const float* e2_w1=(const float*)d_in[10], *e2_b1=(const float*)d_in[11],
             * e2_w2=(const float*)d_in[12], *e2_b2=(const float*)d_in[13],
             * e2_g =(const float*)d_in[14], *e2_be=(const float*)d_in[15];
  const float* e3_w1=(const float*)d_in[16], *e3_b1=(const float*)d_in[17],
             * e3_w2=(const float*)d_in[18], *e3_b2=(const float*)d_in[19],
             * e3_g =(const float*)d_in[20], *e3_be=(const float*)d_in[21];
  const float* e4_w1=(const float*)d_in[22], *e4_b1=(const float*)d_in[23],
             * e4_w2=(const float*)d_in[24], *e4_b2=(const float*)d_in[25],
             * e4_g =(const float*)d_in[26], *e4_be=(const float*)d_in[27];
  const float* fc_w=(const float*)d_in[28], *fc_b=(const float*)d_in[29];
  const float* mw1=(const float*)d_in[30], *mb1=(const float*)d_in[31];
  const float* mw2=(const float*)d_in[32], *mb2=(const float*)d_in[33];
  const float* ow1=(const float*)d_in[34], *ob1=(const float*)d_in[35];
  const float* ow2=(const float*)d_in[36], *ob2=(const float*)d_in[37];
  const float* ow3=(const float*)d_in[38], *ob3=(const float*)d_in[39];

  char* ws = (char*)d_ws;
  size_t off = 0;
  auto alloc = [&](size_t bytes)->void*{ void* p = ws + off; off = (off + bytes + 255) & ~(size_t)255; return p; };
  bf16* W2ABT= (bf16*)alloc((size_t)131072*2);
  bf16* W2BT = (bf16*)alloc((size_t)65536*2);
  bf16* W4ABT= (bf16*)alloc((size_t)131072*2);
  bf16* W4CT = (bf16*)alloc((size_t)65536*2);
  bf16* W4BT = (bf16*)alloc((size_t)65536*2);
  bf16* MW2T = (bf16*)alloc((size_t)262144*2);
  bf16* OW1T = (bf16*)alloc((size_t)73728*2);
  bf16* OW2T = (bf16*)alloc((size_t)65536*2);
  float* BIAS2=(float*)alloc((size_t)512*4);
  float* BIAS4=(float*)alloc((size_t)512*4);
  float* ZEROB=(float*)alloc((size_t)256*4);
  bf16* X1   = (bf16*)alloc((size_t)65536*2);
  float* HS  = (float*)alloc((size_t)65536*4);
  bf16* X3   = (bf16*)alloc((size_t)65536*2);
  bf16* SR2  = (bf16*)alloc((size_t)131072*2);
  bf16* SR4  = (bf16*)alloc((size_t)131072*2);
  float* Z4  = (float*)alloc((size_t)7936*256*4);
  bf16* YBF  = (bf16*)alloc((size_t)12544*256*2);
  float* YF32= (float*)alloc((size_t)7936*256*4);
  bf16* X2   = (bf16*)alloc((size_t)7936*256*2);
  bf16* X4   = (bf16*)alloc((size_t)7936*256*2);
  bf16* P2   = (bf16*)alloc((size_t)12544*256*2);
  float* INC = (float*)alloc((size_t)65536*4);
  float* RT  = (float*)alloc((size_t)7936*4*4);
  float* PART= (float*)alloc((size_t)248*512*4);
  float* PRM = (float*)alloc((size_t)512*4);
  bf16* AAUG = (bf16*)alloc((size_t)12544*288*2);

  float* out = (float*)d_out;
  float* prob_out = out + 49152;

  prep_weights<<<3365,256,0,stream>>>(e2_w1,e2_w2,e4_w1,e4_w2,mw2,ow1,ow2,e2_b1,e4_b1,
                                      W2ABT,W2BT,W4ABT,W4CT,W4BT,MW2T,OW1T,OW2T,BIAS2,BIAS4,ZEROB);
  small_mlp<196><<<256,256,0,stream>>>(data, e1_w1,e1_b1,e1_w2,e1_b2, HS);
  bn_small<<<1,256,0,stream>>>(HS, e1_g, e1_be, X1);
  gemm_mfma<256,512,0,true,32,false><<<8,256,0,stream>>>(X1, W2ABT, BIAS2, SR2, nullptr);
  combine2<<<992,256,0,stream>>>(SR2, YBF);
  gemm_mfma<256,256,2,false,32,true><<<248,256,0,stream>>>(YBF, W2BT, e2_b2, YF32, PART);
  bn_finalize<<<1,256,0,stream>>>(PART, 248, e2_g, e2_be, PRM, 7936.f);
  bn_apply<<<992,256,0,stream>>>(YF32, PRM, X2);
  seg_incoming<<<256,256,0,stream>>>(X2, INC);
  small_mlp<256><<<256,256,0,stream>>>(INC, e3_w1,e3_b1,e3_w2,e3_b2, HS);
  bn_small<<<1,256,0,stream>>>(HS, e3_g, e3_be, X3);
  gemm_mfma<256,512,0,true,32,false><<<8,256,0,stream>>>(X3, W4ABT, BIAS4, SR4, nullptr);
  gemm_mfma<256,256,0,false,32,false><<<248,256,0,stream>>>(X2, W4CT, ZEROB, Z4, nullptr);
  combine4<<<992,256,0,stream>>>(SR4, Z4, YBF);
  gemm_mfma<256,256,2,false,32,true><<<248,256,0,stream>>>(YBF, W4BT, e4_b2, YF32, PART);
  bn_finalize<<<1,256,0,stream>>>(PART, 248, e4_g, e4_be, PRM, 7936.f);
  bn_apply<<<992,256,0,stream>>>(YF32, PRM, X4);
  fc_softmax<<<31,256,0,stream>>>(X4, fc_w, fc_b, gumbel, prob_out, RT);
  decoder_msg<<<6272,256,0,stream>>>(data, RT, mw1, mb1, MW2T, mb2, AAUG);
  gemm_mfma<288,256,1,true,32,false><<<392,256,0,stream>>>(AAUG, OW1T, ob1, YBF, nullptr);
  gemm_mfma<256,256,1,true,32,false><<<392,256,0,stream>>>(YBF, OW2T, ob2, P2, nullptr);
  final_out<<<49,256,0,stream>>>(P2, ow3, ob3, data, out);
}

// Round 7
// 660.653 us; speedup vs baseline: 1.2715x; 1.2112x over previous
//
#include <hip/hip_runtime.h>
#include <hip/hip_bf16.h>

#define NNODES 32
#define TSTEPS 49
#define NEDGE  992
#define ROWS_E 7936     // B*E
#define ROWS_OUT 12544  // B*T*N
#define EPSV 1e-5f

typedef __hip_bfloat16 bf16;
typedef __attribute__((ext_vector_type(8))) short bf16x8;
typedef __attribute__((ext_vector_type(4))) float f32x4;

__device__ inline float eluf(float x){ return x > 0.f ? x : (__expf(x) - 1.f); }
__device__ inline float bfu2f(unsigned short u){ unsigned v = ((unsigned)u) << 16; return *reinterpret_cast<float*>(&v); }
__device__ inline unsigned cvt_pk_bf16(float lo, float hi){
  unsigned r;
  asm("v_cvt_pk_bf16_f32 %0, %1, %2" : "=v"(r) : "v"(lo), "v"(hi));
  return r;
}

// ---------------- weight prep: transpose + bf16 convert + bias builds ----------------
__global__ void prep_weights(const float* e2w1, const float* e2w2, const float* e4w1, const float* e4w2,
                             const float* mw2, const float* ow1, const float* ow2,
                             const float* e2b1, const float* e4b1,
                             bf16* w2abT, bf16* w2bT, bf16* w4abT, bf16* w4cT, bf16* w4bT,
                             bf16* mw2T, bf16* ow1T, bf16* ow2T,
                             float* bias2, float* bias4, float* zerob){
  int i = blockIdx.x*256 + threadIdx.x;
  if (i < 131072){ int n=i>>8, c=i&255;
    w2abT[i] = __float2bfloat16(n<256 ? e2w1[c*256+n] : e2w1[(256+c)*256 + (n-256)]); return;} i-=131072;
  if (i < 65536){ int n=i>>8,c=i&255; w2bT[i]=__float2bfloat16(e2w2[c*256+n]); return;} i-=65536;
  if (i < 131072){ int n=i>>8,c=i&255;
    w4abT[i]=__float2bfloat16(n<256 ? e4w1[c*256+n] : e4w1[(256+c)*256+(n-256)]); return;} i-=131072;
  if (i < 65536){ int n=i>>8,c=i&255; w4cT[i]=__float2bfloat16(e4w1[(512+c)*256+n]); return;} i-=65536;
  if (i < 65536){ int n=i>>8,c=i&255; w4bT[i]=__float2bfloat16(e4w2[c*256+n]); return;} i-=65536;
  if (i < 262144){ int k=i>>16, r=i&65535; int n=r>>8,c=r&255;
    mw2T[i]=__float2bfloat16(mw2[(k*256+c)*256+n]); return;} i-=262144;
  if (i < 73728){ int n=i/288, c=i%288;
    ow1T[i]= (c<260)?__float2bfloat16(ow1[c*256+n]):__float2bfloat16(0.f); return;} i-=73728;
  if (i < 65536){ int n=i>>8,c=i&255; ow2T[i]=__float2bfloat16(ow2[c*256+n]); return;} i-=65536;
  if (i < 512){ bias2[i] = (i<256)?e2b1[i]:0.f; return;} i-=512;
  if (i < 512){ bias4[i] = (i<256)?e4b1[i]:0.f; return;} i-=512;
  if (i < 256){ zerob[i]=0.f; return; }
}

// ---------------- small 2-layer ELU MLP (256 rows), fp32 VALU ----------------
template<int KIN>
__global__ void small_mlp(const float* __restrict__ X, const float* __restrict__ w1, const float* __restrict__ b1,
                          const float* __restrict__ w2, const float* __restrict__ b2, float* __restrict__ H){
  __shared__ float xs[KIN];
  __shared__ float h1[256];
  int r = blockIdx.x, f = threadIdx.x;
  for (int c = f; c < KIN; c += 256) xs[c] = X[(size_t)r*KIN + c];
  __syncthreads();
  float acc = b1[f];
  for (int c = 0; c < KIN; c++) acc = fmaf(xs[c], w1[c*256+f], acc);
  h1[f] = eluf(acc);
  __syncthreads();
  float a2 = b2[f];
  for (int c = 0; c < 256; c++) a2 = fmaf(h1[c], w2[c*256+f], a2);
  H[(size_t)r*256 + f] = eluf(a2);
}

// BN over 256 rows (single block); writes bf16 normalized
__global__ void bn_small(const float* __restrict__ H, const float* __restrict__ g, const float* __restrict__ be,
                         bf16* __restrict__ Xout){
  int f = threadIdx.x;
  float s = 0.f, s2 = 0.f;
  for (int r = 0; r < 256; r++){ float v = H[r*256+f]; s += v; s2 += v*v; }
  float m = s * (1.f/256.f), var = s2 * (1.f/256.f) - m*m;
  float sc = g[f] * rsqrtf(var + EPSV), sh = be[f] - m*sc;
  for (int r = 0; r < 256; r++) Xout[r*256+f] = __float2bfloat16(H[r*256+f]*sc + sh);
}

// ---------------- generic MFMA GEMM: Y = act(A @ W + b) ----------------
template<int K, int NCOLS, int ACT, bool OBF, int MT, bool STATS>
__global__ __launch_bounds__(256,4) void gemm_mfma(const bf16* __restrict__ A, const bf16* __restrict__ WT,
                                                   const float* __restrict__ bias, void* __restrict__ Y,
                                                   float* __restrict__ part){
  constexpr int NTW = NCOLS/64;           // n-tiles per wave
  int mb = blockIdx.x;
  int tid = threadIdx.x;
  int w = tid >> 6, l = tid & 63, l15 = l & 15, lq = l >> 4;
  f32x4 acc[MT/16][NTW];
  #pragma unroll
  for (int m = 0; m < MT/16; m++)
    #pragma unroll
    for (int nt = 0; nt < NTW; nt++) acc[m][nt] = (f32x4){0.f,0.f,0.f,0.f};
  const bf16* Ab = A + (size_t)mb*MT*K;
  int nw = w*(NCOLS/4);
  for (int s = 0; s < K/32; s++){
    int c0 = s*32 + lq*8;
    bf16x8 bfr[NTW];
    #pragma unroll
    for (int nt = 0; nt < NTW; nt++){
      int fcol = nw + nt*16 + l15;
      bfr[nt] = *reinterpret_cast<const bf16x8*>(WT + (size_t)fcol*K + c0);
    }
    #pragma unroll
    for (int m = 0; m < MT/16; m++){
      bf16x8 afr = *reinterpret_cast<const bf16x8*>(Ab + (size_t)(m*16 + l15)*K + c0);
      #pragma unroll
      for (int nt = 0; nt < NTW; nt++)
        acc[m][nt] = __builtin_amdgcn_mfma_f32_16x16x32_bf16(afr, bfr[nt], acc[m][nt], 0, 0, 0);
    }
  }
  #pragma unroll
  for (int nt = 0; nt < NTW; nt++){
    int fcol = nw + nt*16 + l15;
    float bv = bias[fcol];
    float cs = 0.f, cs2 = 0.f;
    #pragma unroll
    for (int m = 0; m < MT/16; m++){
      #pragma unroll
      for (int v = 0; v < 4; v++){
        int row = mb*MT + m*16 + lq*4 + v;
        float val = acc[m][nt][v] + bv;
        if (ACT == 1) val = fmaxf(val, 0.f);
        else if (ACT == 2) val = eluf(val);
        if (OBF) ((bf16*)Y)[(size_t)row*NCOLS + fcol] = __float2bfloat16(val);
        else     ((float*)Y)[(size_t)row*NCOLS + fcol] = val;
        if (STATS){ cs += val; cs2 += val*val; }
      }
    }
    if (STATS){
      cs  += __shfl_xor(cs, 16);  cs  += __shfl_xor(cs, 32);
      cs2 += __shfl_xor(cs2, 16); cs2 += __shfl_xor(cs2, 32);
      if (l < 16){ part[(size_t)mb*512 + fcol] = cs; part[(size_t)mb*512 + 256 + fcol] = cs2; }
    }
  }
}

// ---------------- edge combiners ----------------
__global__ void combine2(const bf16* __restrict__ SR, bf16* __restrict__ Y){
  int i = blockIdx.x*256 + threadIdx.x;   // 7936*32 chunks
  int row = i >> 5, c8 = (i & 31)*8;
  int b = row / NEDGE, e = row % NEDGE;
  int rc = e / 31, jj = e % 31;
  int sn = jj + (jj >= rc);
  bf16x8 s8 = *reinterpret_cast<const bf16x8*>(SR + (size_t)(b*NNODES + sn)*512 + c8);
  bf16x8 r8 = *reinterpret_cast<const bf16x8*>(SR + (size_t)(b*NNODES + rc)*512 + 256 + c8);
  bf16x8 o;
  #pragma unroll
  for (int k = 0; k < 8; k++){
    float v = bfu2f((unsigned short)s8[k]) + bfu2f((unsigned short)r8[k]);
    v = eluf(v);
    __hip_bfloat16 h = __float2bfloat16(v);
    o[k] = *reinterpret_cast<short*>(&h);
  }
  *reinterpret_cast<bf16x8*>(Y + (size_t)row*256 + c8) = o;
}

__global__ void combine4(const bf16* __restrict__ SR, const float* __restrict__ Z, bf16* __restrict__ Y){
  int i = blockIdx.x*256 + threadIdx.x;
  int row = i >> 5, c8 = (i & 31)*8;
  int b = row / NEDGE, e = row % NEDGE;
  int rc = e / 31, jj = e % 31;
  int sn = jj + (jj >= rc);
  bf16x8 s8 = *reinterpret_cast<const bf16x8*>(SR + (size_t)(b*NNODES + sn)*512 + c8);
  bf16x8 r8 = *reinterpret_cast<const bf16x8*>(SR + (size_t)(b*NNODES + rc)*512 + 256 + c8);
  const float* zp = Z + (size_t)row*256 + c8;
  float4 z0 = *reinterpret_cast<const float4*>(zp);
  float4 z1 = *reinterpret_cast<const float4*>(zp+4);
  float zz[8] = {z0.x,z0.y,z0.z,z0.w,z1.x,z1.y,z1.z,z1.w};
  bf16x8 o;
  #pragma unroll
  for (int k = 0; k < 8; k++){
    float v = bfu2f((unsigned short)s8[k]) + bfu2f((unsigned short)r8[k]) + zz[k];
    v = eluf(v);
    __hip_bfloat16 h = __float2bfloat16(v);
    o[k] = *reinterpret_cast<short*>(&h);
  }
  *reinterpret_cast<bf16x8*>(Y + (size_t)row*256 + c8) = o;
}

// ---------------- batchnorm finalize/apply ----------------
__global__ void bn_finalize(const float* __restrict__ part, int nb, const float* __restrict__ g,
                            const float* __restrict__ be, float* __restrict__ prm, float nrows){
  int f = threadIdx.x;
  float s = 0.f, s2 = 0.f;
  for (int i = 0; i < nb; i++){ s += part[(size_t)i*512+f]; s2 += part[(size_t)i*512+256+f]; }
  float m = s / nrows, var = s2 / nrows - m*m;
  float sc = g[f] * rsqrtf(var + EPSV);
  prm[f] = sc; prm[256+f] = be[f] - m*sc;
}
__global__ void bn_apply(const float* __restrict__ Y, const float* __restrict__ prm, bf16* __restrict__ X){
  int i = blockIdx.x*256 + threadIdx.x;    // 7936*32 chunks of 8
  int c8 = (i & 31)*8;
  const float* yp = Y + (size_t)i*8;
  float4 a0 = *reinterpret_cast<const float4*>(yp);
  float4 a1 = *reinterpret_cast<const float4*>(yp+4);
  float4 s0 = *reinterpret_cast<const float4*>(prm + c8);
  float4 s1 = *reinterpret_cast<const float4*>(prm + c8 + 4);
  float4 h0 = *reinterpret_cast<const float4*>(prm + 256 + c8);
  float4 h1 = *reinterpret_cast<const float4*>(prm + 256 + c8 + 4);
  float vals[8] = {a0.x*s0.x+h0.x, a0.y*s0.y+h0.y, a0.z*s0.z+h0.z, a0.w*s0.w+h0.w,
                   a1.x*s1.x+h1.x, a1.y*s1.y+h1.y, a1.z*s1.z+h1.z, a1.w*s1.w+h1.w};
  bf16x8 o;
  #pragma unroll
  for (int k = 0; k < 8; k++){
    __hip_bfloat16 h = __float2bfloat16(vals[k]);
    o[k] = *reinterpret_cast<short*>(&h);
  }
  *reinterpret_cast<bf16x8*>(X + (size_t)i*8) = o;
}

// ---------------- incoming = segment-sum over 31 edges / N ----------------
__global__ void seg_incoming(const bf16* __restrict__ X2, float* __restrict__ inc){
  int bn = blockIdx.x; int b = bn >> 5, n = bn & 31;
  int f = threadIdx.x;
  const bf16* p = X2 + (size_t)(b*NEDGE + n*31)*256 + f;
  float s = 0.f;
  for (int j = 0; j < 31; j++) s += __bfloat162float(p[j*256]);
  inc[bn*256 + f] = s * (1.f/32.f);
}

// ---------------- fc + softmax (prob out, rel_type to ws) ----------------
__global__ void fc_softmax(const bf16* __restrict__ X4, const float* __restrict__ fcw, const float* __restrict__ fcb,
                           const float* __restrict__ gumbel, float* __restrict__ prob_out, float* __restrict__ rt){
  int r = blockIdx.x*256 + threadIdx.x;
  if (r >= ROWS_E) return;
  float l0 = fcb[0], l1 = fcb[1], l2 = fcb[2], l3 = fcb[3];
  const bf16* xr = X4 + (size_t)r*256;
  for (int c = 0; c < 256; c += 8){
    uint4 u = *reinterpret_cast<const uint4*>(xr + c);
    unsigned uu[4] = {u.x, u.y, u.z, u.w};
    #pragma unroll
    for (int q = 0; q < 4; q++){
      float x0 = bfu2f((unsigned short)(uu[q] & 0xffff));
      float x1 = bfu2f((unsigned short)(uu[q] >> 16));
      int cc = c + 2*q;
      float4 w0 = *reinterpret_cast<const float4*>(fcw + cc*4);
      float4 w1 = *reinterpret_cast<const float4*>(fcw + (cc+1)*4);
      l0 += x0*w0.x + x1*w1.x; l1 += x0*w0.y + x1*w1.y;
      l2 += x0*w0.z + x1*w1.z; l3 += x0*w0.w + x1*w1.w;
    }
  }
  float mx = fmaxf(fmaxf(l0,l1), fmaxf(l2,l3));
  float e0 = __expf(l0-mx), e1 = __expf(l1-mx), e2 = __expf(l2-mx), e3 = __expf(l3-mx);
  float inv = 1.f / (e0+e1+e2+e3);
  prob_out[(size_t)r*4+0] = e0*inv; prob_out[(size_t)r*4+1] = e1*inv;
  prob_out[(size_t)r*4+2] = e2*inv; prob_out[(size_t)r*4+3] = e3*inv;
  float4 gv = *reinterpret_cast<const float4*>(gumbel + (size_t)r*4);
  float t0 = (l0+gv.x)*2.f, t1 = (l1+gv.y)*2.f, t2 = (l2+gv.z)*2.f, t3 = (l3+gv.w)*2.f;
  float mx2 = fmaxf(fmaxf(t0,t1), fmaxf(t2,t3));
  float f0 = __expf(t0-mx2), f1 = __expf(t1-mx2), f2 = __expf(t2-mx2), f3 = __expf(t3-mx2);
  float inv2 = 1.f / (f0+f1+f2+f3);
  rt[(size_t)r*4+0] = f0*inv2; rt[(size_t)r*4+1] = f1*inv2;
  rt[(size_t)r*4+2] = f2*inv2; rt[(size_t)r*4+3] = f3*inv2;
}

// ---------------- fused decoder message passing v9 ----------------
// Fragment-direct: no hA. S (32 nodes, f32, swizzled) + R (2 receivers, f32) in LDS;
// MFMA A-fragments assembled at consume time (2x b128 S + broadcast R + add/relu/cvt_pk).
// 2 barriers/kk. LDS ~37.5KB -> 4 blocks/CU, 16 waves/CU.
// Pad rows (aj==31) need no masking: their rel_type is 0 in the epilogue; snd clamped for addr safety.
__global__ __launch_bounds__(256,4) void decoder_msg(
    const float* __restrict__ data, const float* __restrict__ rt,
    const float* __restrict__ mw1, const float* __restrict__ mb1,
    const bf16* __restrict__ mw2T, const float* __restrict__ mb2,
    bf16* __restrict__ Aaug){
  __shared__ __align__(16) float Sf[32*256];    // 32KB, xor-swizzled (8B granule)
  __shared__ __align__(16) float Rf[2*256];     // 2KB
  __shared__ __align__(16) float xn[32][4];
  __shared__ __align__(16) float rts_s[64][4];
  __shared__ __align__(16) float aggl[2][256];
  int bx = blockIdx.x;
  int bt = bx >> 4, rg = bx & 15;
  int b = bt / TSTEPS, t = bt % TSTEPS;
  int n0 = rg * 2;
  int tid = threadIdx.x;
  int w = tid >> 6, l = tid & 63, l15 = l & 15, lq = l >> 4;

  if (tid < 32){
    *reinterpret_cast<float4*>(&xn[tid][0]) =
        *reinterpret_cast<const float4*>(data + ((size_t)(b*NNODES + tid)*TSTEPS + t)*4);
  } else if (tid >= 64 && tid < 128){
    int r = tid - 64;
    int n = n0 + (r >> 5), j = r & 31;
    float4 rv = make_float4(0.f,0.f,0.f,0.f);
    if (j < 31) rv = *reinterpret_cast<const float4*>(rt + ((size_t)(b*NEDGE + n*31 + j))*4);
    *reinterpret_cast<float4*>(&rts_s[r][0]) = rv;
  }
  for (int i = tid; i < 512; i += 256) ((float*)aggl)[i] = 0.f;
  __syncthreads();

  int c2 = tid & 127;      // col pair 2c2, 2c2+1 (phase 1)
  int nh = tid >> 7;       // node half / receiver index (phase 1)

  for (int kk = 1; kk < 4; kk++){
    { // ---- phase 1: S (f32, swizzled) + R (f32) -> LDS ----
      float2 a0 = *reinterpret_cast<const float2*>(mw1 + (size_t)(kk*8+0)*256 + 2*c2);
      float2 a1 = *reinterpret_cast<const float2*>(mw1 + (size_t)(kk*8+1)*256 + 2*c2);
      float2 a2 = *reinterpret_cast<const float2*>(mw1 + (size_t)(kk*8+2)*256 + 2*c2);
      float2 a3 = *reinterpret_cast<const float2*>(mw1 + (size_t)(kk*8+3)*256 + 2*c2);
      float2 a4 = *reinterpret_cast<const float2*>(mw1 + (size_t)(kk*8+4)*256 + 2*c2);
      float2 a5 = *reinterpret_cast<const float2*>(mw1 + (size_t)(kk*8+5)*256 + 2*c2);
      float2 a6 = *reinterpret_cast<const float2*>(mw1 + (size_t)(kk*8+6)*256 + 2*c2);
      float2 a7 = *reinterpret_cast<const float2*>(mw1 + (size_t)(kk*8+7)*256 + 2*c2);
      float2 bb = *reinterpret_cast<const float2*>(mb1 + kk*256 + 2*c2);
      char* Sb = reinterpret_cast<char*>(Sf);
      #pragma unroll
      for (int ii = 0; ii < 16; ii++){
        int nd = nh*16 + ii;
        float4 x = *reinterpret_cast<float4*>(&xn[nd][0]);
        float2 sv;
        sv.x = fmaf(x.x,a0.x, fmaf(x.y,a1.x, fmaf(x.z,a2.x, fmaf(x.w,a3.x, bb.x))));
        sv.y = fmaf(x.x,a0.y, fmaf(x.y,a1.y, fmaf(x.z,a2.y, fmaf(x.w,a3.y, bb.y))));
        *reinterpret_cast<float2*>(Sb + nd*1024 + ((8*c2) ^ ((nd&7)<<4))) = sv;
      }
      float4 xr = *reinterpret_cast<float4*>(&xn[n0+nh][0]);
      float2 rv;
      rv.x = fmaf(xr.x,a4.x, fmaf(xr.y,a5.x, fmaf(xr.z,a6.x, xr.w*a7.x)));
      rv.y = fmaf(xr.x,a4.y, fmaf(xr.y,a5.y, fmaf(xr.z,a6.y, xr.w*a7.y)));
      *reinterpret_cast<float2*>(Rf + nh*256 + 2*c2) = rv;
    }
    __syncthreads();

    // ---- phase 2: MFMA with fragment-direct A ----
    f32x4 acc[4][4];
    #pragma unroll
    for (int m = 0; m < 4; m++)
      #pragma unroll
      for (int nt = 0; nt < 4; nt++) acc[m][nt] = (f32x4){0.f,0.f,0.f,0.f};
    const bf16* wk = mw2T + (size_t)kk*65536;
    const char* Sb = reinterpret_cast<const char*>(Sf);
    for (int s = 0; s < 8; s++){
      int c0 = s*32 + lq*8;
      bf16x8 bfr[4];
      #pragma unroll
      for (int nt = 0; nt < 4; nt++){
        int fcol = w*64 + nt*16 + l15;
        bfr[nt] = *reinterpret_cast<const bf16x8*>(wk + (size_t)fcol*256 + c0);
      }
      #pragma unroll
      for (int m = 0; m < 4; m++){
        int rgm = m >> 1;                  // receiver index (wave-uniform)
        int aj = (m & 1)*16 + l15;         // edge slot within receiver
        int recvn = n0 + rgm;
        int sv = aj + (aj >= recvn);
        if (sv > 31) sv = 31;              // pad row: garbage OK (rt=0), clamp for safety
        const char* srow = Sb + sv*1024;
        int sw = (sv & 7) << 4;
        float4 sA = *reinterpret_cast<const float4*>(srow + ((4*c0) ^ sw));
        float4 sB = *reinterpret_cast<const float4*>(srow + ((4*c0+16) ^ sw));
        const float* rrow = Rf + rgm*256 + c0;
        float4 rA = *reinterpret_cast<const float4*>(rrow);
        float4 rB = *reinterpret_cast<const float4*>(rrow + 4);
        union { unsigned u[4]; bf16x8 v; } af;
        af.u[0] = cvt_pk_bf16(fmaxf(sA.x+rA.x,0.f), fmaxf(sA.y+rA.y,0.f));
        af.u[1] = cvt_pk_bf16(fmaxf(sA.z+rA.z,0.f), fmaxf(sA.w+rA.w,0.f));
        af.u[2] = cvt_pk_bf16(fmaxf(sB.x+rB.x,0.f), fmaxf(sB.y+rB.y,0.f));
        af.u[3] = cvt_pk_bf16(fmaxf(sB.z+rB.z,0.f), fmaxf(sB.w+rB.w,0.f));
        #pragma unroll
        for (int nt = 0; nt < 4; nt++)
          acc[m][nt] = __builtin_amdgcn_mfma_f32_16x16x32_bf16(af.v, bfr[nt], acc[m][nt], 0, 0, 0);
      }
    }
    // ---- epilogue: relu(+b2) * rel_type, column-reduce into per-receiver agg ----
    #pragma unroll
    for (int m = 0; m < 4; m++){
      int g = m >> 1;
      #pragma unroll
      for (int nt = 0; nt < 4; nt++){
        int fcol = w*64 + nt*16 + l15;
        float bv = mb2[kk*256 + fcol];
        float ssum = 0.f;
        #pragma unroll
        for (int v = 0; v < 4; v++){
          int rowa = m*16 + lq*4 + v;
          float msg = fmaxf(acc[m][nt][v] + bv, 0.f);
          ssum += msg * rts_s[rowa][kk];
        }
        ssum += __shfl_xor(ssum, 16);
        ssum += __shfl_xor(ssum, 32);
        if (lq == 0) aggl[g][fcol] += ssum;
      }
    }
    __syncthreads();   // Sf/Rf free for next kk; aggl committed
  }

  // write aug rows: [data(4) | agg(256) | pad(28)] bf16, K=288
  for (int i = tid; i < 2*288; i += 256){
    int g = i / 288, c = i % 288;
    float val;
    if (c < 4)        val = xn[n0+g][c];
    else if (c < 260) val = aggl[g][c-4];
    else              val = 0.f;
    Aaug[(size_t)(bt*NNODES + n0 + g)*288 + c] = __float2bfloat16(val);
  }
}

// ---------------- final: p3 = P2 @ ow3 + ob3 ; out = data + p3 (t<48) ----------------
__global__ void final_out(const bf16* __restrict__ P2, const float* __restrict__ ow3,
                          const float* __restrict__ ob3, const float* __restrict__ data,
                          float* __restrict__ out){
  int r = blockIdx.x*256 + threadIdx.x;
  if (r >= ROWS_OUT) return;
  int bt = r >> 5, n = r & 31;
  int b = bt / TSTEPS, t = bt % TSTEPS;
  float a0 = ob3[0], a1 = ob3[1], a2 = ob3[2], a3 = ob3[3];
  const bf16* pr = P2 + (size_t)r*256;
  for (int c = 0; c < 256; c += 8){
    uint4 u = *reinterpret_cast<const uint4*>(pr + c);
    unsigned uu[4] = {u.x, u.y, u.z, u.w};
    #pragma unroll
    for (int q = 0; q < 4; q++){
      float x0 = bfu2f((unsigned short)(uu[q] & 0xffff));
      float x1 = bfu2f((unsigned short)(uu[q] >> 16));
      int cc = c + 2*q;
      float4 w0 = *reinterpret_cast<const float4*>(ow3 + cc*4);
      float4 w1 = *reinterpret_cast<const float4*>(ow3 + (cc+1)*4);
      a0 += x0*w0.x + x1*w1.x; a1 += x0*w0.y + x1*w1.y;
      a2 += x0*w0.z + x1*w1.z; a3 += x0*w0.w + x1*w1.w;
    }
  }
  if (t < TSTEPS-1){
    float4 dv = *reinterpret_cast<const float4*>(data + ((size_t)(b*NNODES + n)*TSTEPS + t)*4);
    float4 o; o.x = dv.x + a0; o.y = dv.y + a1; o.z = dv.z + a2; o.w = dv.w + a3;
    *reinterpret_cast<float4*>(out + ((size_t)(b*NNODES + n)*(TSTEPS-1) + t)*4) = o;
  }
}

// ---------------- launcher ----------------
extern "C" void kernel_launch(void* const* d_in, const int* in_sizes, int n_in,
                              void* d_out, int out_size, void* d_ws, size_t ws_size,
                              hipStream_t stream){
  const float* data    = (const float*)d_in[0];
  const float* gumbel  = (const float*)d_in[1];
  const float* e1_w1=(const float*)d_in[4],  *e1_b1=(const float*)d_in[5],
             * e1_w2=(const float*)d_in[6],  *e1_b2=(const float*)d_in[7],
             * e1_g =(const float*)d_in[8],  *e1_be=(const float*)d_in[9];
  const float* e2_w1=(const float*)d_in[10], *e2_b1=(const float*)d_in[11],
             * e2_w2=(const float*)d_in[12], *e2_b2=(const float*)d_in[13],
             * e2_g =(const float*)d_in[14], *e2_be=(const float*)d_in[15];
  const float* e3_w1=(const float*)d_in[16], *e3_b1=(const float*)d_in[17],
             * e3_w2=(const float*)d_in[18], *e3_b2=(const float*)d_in[19],
             * e3_g =(const float*)d_in[20], *e3_be=(const float*)d_in[21];
  const float* e4_w1=(const float*)d_in[22], *e4_b1=(const float*)d_in[23],
             * e4_w2=(const float*)d_in[24], *e4_b2=(const float*)d_in[25],
             * e4_g =(const float*)d_in[26], *e4_be=(const float*)d_in[27];
  const float* fc_w=(const float*)d_in[28], *fc_b=(const float*)d_in[29];
  const float* mw1=(const float*)d_in[30], *mb1=(const float*)d_in[31];
  const float* mw2=(const float*)d_in[32], *mb2=(const float*)d_in[33];
  const float* ow1=(const float*)d_in[34], *ob1=(const float*)d_in[35];
  const float* ow2=(const float*)d_in[36], *ob2=(const float*)d_in[37];
  const float* ow3=(const float*)d_in[38], *ob3=(const float*)d_in[39];

  char* ws = (char*)d_ws;
  size_t off = 0;
  auto alloc = [&](size_t bytes)->void*{ void* p = ws + off; off = (off + bytes + 255) & ~(size_t)255; return p; };
  bf16* W2ABT= (bf16*)alloc((size_t)131072*2);
  bf16* W2BT = (bf16*)alloc((size_t)65536*2);
  bf16* W4ABT= (bf16*)alloc((size_t)131072*2);
  bf16* W4CT = (bf16*)alloc((size_t)65536*2);
  bf16* W4BT = (bf16*)alloc((size_t)65536*2);
  bf16* MW2T = (bf16*)alloc((size_t)262144*2);
  bf16* OW1T = (bf16*)alloc((size_t)73728*2);
  bf16* OW2T = (bf16*)alloc((size_t)65536*2);
  float* BIAS2=(float*)alloc((size_t)512*4);
  float* BIAS4=(float*)alloc((size_t)512*4);
  float* ZEROB=(float*)alloc((size_t)256*4);
  bf16* X1   = (bf16*)alloc((size_t)65536*2);
  float* HS  = (float*)alloc((size_t)65536*4);
  bf16* X3   = (bf16*)alloc((size_t)65536*2);
  bf16* SR2  = (bf16*)alloc((size_t)131072*2);
  bf16* SR4  = (bf16*)alloc((size_t)131072*2);
  float* Z4  = (float*)alloc((size_t)7936*256*4);
  bf16* YBF  = (bf16*)alloc((size_t)12544*256*2);
  float* YF32= (float*)alloc((size_t)7936*256*4);
  bf16* X2   = (bf16*)alloc((size_t)7936*256*2);
  bf16* X4   = (bf16*)alloc((size_t)7936*256*2);
  bf16* P2   = (bf16*)alloc((size_t)12544*256*2);
  float* INC = (float*)alloc((size_t)65536*4);
  float* RT  = (float*)alloc((size_t)7936*4*4);
  float* PART= (float*)alloc((size_t)248*512*4);
  float* PRM = (float*)alloc((size_t)512*4);
  bf16* AAUG = (bf16*)alloc((size_t)12544*288*2);

  float* out = (float*)d_out;
  float* prob_out = out + 49152;

  prep_weights<<<3365,256,0,stream>>>(e2_w1,e2_w2,e4_w1,e4_w2,mw2,ow1,ow2,e2_b1,e4_b1,
                                      W2ABT,W2BT,W4ABT,W4CT,W4BT,MW2T,OW1T,OW2T,BIAS2,BIAS4,ZEROB);
  small_mlp<196><<<256,256,0,stream>>>(data, e1_w1,e1_b1,e1_w2,e1_b2, HS);
  bn_small<<<1,256,0,stream>>>(HS, e1_g, e1_be, X1);
  gemm_mfma<256,512,0,true,32,false><<<8,256,0,stream>>>(X1, W2ABT, BIAS2, SR2, nullptr);
  combine2<<<992,256,0,stream>>>(SR2, YBF);
  gemm_mfma<256,256,2,false,32,true><<<248,256,0,stream>>>(YBF, W2BT, e2_b2, YF32, PART);
  bn_finalize<<<1,256,0,stream>>>(PART, 248, e2_g, e2_be, PRM, 7936.f);
  bn_apply<<<992,256,0,stream>>>(YF32, PRM, X2);
  seg_incoming<<<256,256,0,stream>>>(X2, INC);
  small_mlp<256><<<256,256,0,stream>>>(INC, e3_w1,e3_b1,e3_w2,e3_b2, HS);
  bn_small<<<1,256,0,stream>>>(HS, e3_g, e3_be, X3);
  gemm_mfma<256,512,0,true,32,false><<<8,256,0,stream>>>(X3, W4ABT, BIAS4, SR4, nullptr);
  gemm_mfma<256,256,0,false,32,false><<<248,256,0,stream>>>(X2, W4CT, ZEROB, Z4, nullptr);
  combine4<<<992,256,0,stream>>>(SR4, Z4, YBF);
  gemm_mfma<256,256,2,false,32,true><<<248,256,0,stream>>>(YBF, W4BT, e4_b2, YF32, PART);
  bn_finalize<<<1,256,0,stream>>>(PART, 248, e4_g, e4_be, PRM, 7936.f);
  bn_apply<<<992,256,0,stream>>>(YF32, PRM, X4);
  fc_softmax<<<31,256,0,stream>>>(X4, fc_w, fc_b, gumbel, prob_out, RT);
  decoder_msg<<<6272,256,0,stream>>>(data, RT, mw1, mb1, MW2T, mb2, AAUG);
  gemm_mfma<288,256,1,true,32,false><<<392,256,0,stream>>>(AAUG, OW1T, ob1, YBF, nullptr);
  gemm_mfma<256,256,1,true,32,false><<<392,256,0,stream>>>(YBF, OW2T, ob2, P2, nullptr);
  final_out<<<49,256,0,stream>>>(P2, ow3, ob3, data, out);
}

// Round 8
// 635.600 us; speedup vs baseline: 1.3217x; 1.0394x over previous
//
#include <hip/hip_runtime.h>
#include <hip/hip_bf16.h>

#define NNODES 32
#define TSTEPS 49
#define NEDGE  992
#define NBT    392      // B*T
#define ROWS_E 7936     // B*E
#define ROWS_OUT 12544  // B*T*N
#define EPSV 1e-5f

typedef __hip_bfloat16 bf16;
typedef __attribute__((ext_vector_type(8))) short bf16x8;
typedef __attribute__((ext_vector_type(4))) float f32x4;

__device__ inline float eluf(float x){ return x > 0.f ? x : (__expf(x) - 1.f); }
__device__ inline float bfu2f(unsigned short u){ unsigned v = ((unsigned)u) << 16; return *reinterpret_cast<float*>(&v); }
__device__ inline unsigned cvt_pk_bf16(float lo, float hi){
  unsigned r;
  asm("v_cvt_pk_bf16_f32 %0, %1, %2" : "=v"(r) : "v"(lo), "v"(hi));
  return r;
}
__device__ inline void gload16(const void* g, void* l){
  __builtin_amdgcn_global_load_lds(
      (const __attribute__((address_space(1))) unsigned int*)g,
      (__attribute__((address_space(3))) unsigned int*)l, 16, 0, 0);
}

// ---------------- weight prep: transpose + bf16 convert + bias builds ----------------
__global__ void prep_weights(const float* e2w1, const float* e2w2, const float* e4w1, const float* e4w2,
                             const float* mw2, const float* ow1, const float* ow2,
                             const float* e2b1, const float* e4b1,
                             bf16* w2abT, bf16* w2bT, bf16* w4abT, bf16* w4cT, bf16* w4bT,
                             bf16* mw2T, bf16* ow1T, bf16* ow2T,
                             float* bias2, float* bias4, float* zerob){
  int i = blockIdx.x*256 + threadIdx.x;
  if (i < 131072){ int n=i>>8, c=i&255;
    w2abT[i] = __float2bfloat16(n<256 ? e2w1[c*256+n] : e2w1[(256+c)*256 + (n-256)]); return;} i-=131072;
  if (i < 65536){ int n=i>>8,c=i&255; w2bT[i]=__float2bfloat16(e2w2[c*256+n]); return;} i-=65536;
  if (i < 131072){ int n=i>>8,c=i&255;
    w4abT[i]=__float2bfloat16(n<256 ? e4w1[c*256+n] : e4w1[(256+c)*256+(n-256)]); return;} i-=131072;
  if (i < 65536){ int n=i>>8,c=i&255; w4cT[i]=__float2bfloat16(e4w1[(512+c)*256+n]); return;} i-=65536;
  if (i < 65536){ int n=i>>8,c=i&255; w4bT[i]=__float2bfloat16(e4w2[c*256+n]); return;} i-=65536;
  if (i < 262144){ int k=i>>16, r=i&65535; int n=r>>8,c=r&255;
    mw2T[i]=__float2bfloat16(mw2[(k*256+c)*256+n]); return;} i-=262144;
  if (i < 73728){ int n=i/288, c=i%288;
    ow1T[i]= (c<260)?__float2bfloat16(ow1[c*256+n]):__float2bfloat16(0.f); return;} i-=73728;
  if (i < 65536){ int n=i>>8,c=i&255; ow2T[i]=__float2bfloat16(ow2[c*256+n]); return;} i-=65536;
  if (i < 512){ bias2[i] = (i<256)?e2b1[i]:0.f; return;} i-=512;
  if (i < 512){ bias4[i] = (i<256)?e4b1[i]:0.f; return;} i-=512;
  if (i < 256){ zerob[i]=0.f; return; }
}

// ---------------- decoder S/R precompute: per (kk,b,t) a 32KB tile ----------------
// tile layout (shorts): [0..8191] S, node nd col c at short idx nd*256 + (((2c)^((nd&7)<<4))>>1)  (pre-swizzled)
//                       [8192..16383] R, linear nd*256 + c
__global__ void dec_sr(const float* __restrict__ data, const float* __restrict__ mw1,
                       const float* __restrict__ mb1, unsigned short* __restrict__ SRg){
  __shared__ float xs[32][4];
  int bt = blockIdx.x;
  int b = bt / TSTEPS, t = bt % TSTEPS;
  int c = threadIdx.x;
  if (c < 32)
    *reinterpret_cast<float4*>(&xs[c][0]) =
        *reinterpret_cast<const float4*>(data + ((size_t)(b*NNODES + c)*TSTEPS + t)*4);
  __syncthreads();
  #pragma unroll
  for (int kk = 1; kk < 4; kk++){
    float w0=mw1[(size_t)(kk*8+0)*256+c], w1=mw1[(size_t)(kk*8+1)*256+c],
          w2=mw1[(size_t)(kk*8+2)*256+c], w3=mw1[(size_t)(kk*8+3)*256+c],
          w4=mw1[(size_t)(kk*8+4)*256+c], w5=mw1[(size_t)(kk*8+5)*256+c],
          w6=mw1[(size_t)(kk*8+6)*256+c], w7=mw1[(size_t)(kk*8+7)*256+c];
    float bs = mb1[kk*256+c];
    unsigned short* tile = SRg + ((size_t)(kk-1)*NBT + bt)*16384;
    int sidx = (((2*c) /* ^ applied per nd below */)>>1);  // base col part
    #pragma unroll 4
    for (int nd = 0; nd < 32; nd++){
      float4 x = *reinterpret_cast<float4*>(&xs[nd][0]);
      float sv = fmaf(x.x,w0, fmaf(x.y,w1, fmaf(x.z,w2, fmaf(x.w,w3, bs))));
      float rv = fmaf(x.x,w4, fmaf(x.y,w5, fmaf(x.z,w6, x.w*w7)));
      __hip_bfloat16 hs = __float2bfloat16(sv), hr = __float2bfloat16(rv);
      tile[nd*256 + ((((2*c) ^ ((nd&7)<<4)))>>1)] = *reinterpret_cast<unsigned short*>(&hs);
      tile[8192 + nd*256 + c] = *reinterpret_cast<unsigned short*>(&hr);
    }
    (void)sidx;
  }
}

// ---------------- small 2-layer ELU MLP (256 rows), fp32 VALU ----------------
template<int KIN>
__global__ void small_mlp(const float* __restrict__ X, const float* __restrict__ w1, const float* __restrict__ b1,
                          const float* __restrict__ w2, const float* __restrict__ b2, float* __restrict__ H){
  __shared__ float xs[KIN];
  __shared__ float h1[256];
  int r = blockIdx.x, f = threadIdx.x;
  for (int c = f; c < KIN; c += 256) xs[c] = X[(size_t)r*KIN + c];
  __syncthreads();
  float acc = b1[f];
  for (int c = 0; c < KIN; c++) acc = fmaf(xs[c], w1[c*256+f], acc);
  h1[f] = eluf(acc);
  __syncthreads();
  float a2 = b2[f];
  for (int c = 0; c < 256; c++) a2 = fmaf(h1[c], w2[c*256+f], a2);
  H[(size_t)r*256 + f] = eluf(a2);
}

// BN over 256 rows (single block); writes bf16 normalized
__global__ void bn_small(const float* __restrict__ H, const float* __restrict__ g, const float* __restrict__ be,
                         bf16* __restrict__ Xout){
  int f = threadIdx.x;
  float s = 0.f, s2 = 0.f;
  for (int r = 0; r < 256; r++){ float v = H[r*256+f]; s += v; s2 += v*v; }
  float m = s * (1.f/256.f), var = s2 * (1.f/256.f) - m*m;
  float sc = g[f] * rsqrtf(var + EPSV), sh = be[f] - m*sc;
  for (int r = 0; r < 256; r++) Xout[r*256+f] = __float2bfloat16(H[r*256+f]*sc + sh);
}

// ---------------- generic MFMA GEMM: Y = act(A @ W + b) ----------------
template<int K, int NCOLS, int ACT, bool OBF, int MT, bool STATS>
__global__ __launch_bounds__(256,4) void gemm_mfma(const bf16* __restrict__ A, const bf16* __restrict__ WT,
                                                   const float* __restrict__ bias, void* __restrict__ Y,
                                                   float* __restrict__ part){
  constexpr int NTW = NCOLS/64;           // n-tiles per wave
  int mb = blockIdx.x;
  int tid = threadIdx.x;
  int w = tid >> 6, l = tid & 63, l15 = l & 15, lq = l >> 4;
  f32x4 acc[MT/16][NTW];
  #pragma unroll
  for (int m = 0; m < MT/16; m++)
    #pragma unroll
    for (int nt = 0; nt < NTW; nt++) acc[m][nt] = (f32x4){0.f,0.f,0.f,0.f};
  const bf16* Ab = A + (size_t)mb*MT*K;
  int nw = w*(NCOLS/4);
  for (int s = 0; s < K/32; s++){
    int c0 = s*32 + lq*8;
    bf16x8 bfr[NTW];
    #pragma unroll
    for (int nt = 0; nt < NTW; nt++){
      int fcol = nw + nt*16 + l15;
      bfr[nt] = *reinterpret_cast<const bf16x8*>(WT + (size_t)fcol*K + c0);
    }
    #pragma unroll
    for (int m = 0; m < MT/16; m++){
      bf16x8 afr = *reinterpret_cast<const bf16x8*>(Ab + (size_t)(m*16 + l15)*K + c0);
      #pragma unroll
      for (int nt = 0; nt < NTW; nt++)
        acc[m][nt] = __builtin_amdgcn_mfma_f32_16x16x32_bf16(afr, bfr[nt], acc[m][nt], 0, 0, 0);
    }
  }
  #pragma unroll
  for (int nt = 0; nt < NTW; nt++){
    int fcol = nw + nt*16 + l15;
    float bv = bias[fcol];
    float cs = 0.f, cs2 = 0.f;
    #pragma unroll
    for (int m = 0; m < MT/16; m++){
      #pragma unroll
      for (int v = 0; v < 4; v++){
        int row = mb*MT + m*16 + lq*4 + v;
        float val = acc[m][nt][v] + bv;
        if (ACT == 1) val = fmaxf(val, 0.f);
        else if (ACT == 2) val = eluf(val);
        if (OBF) ((bf16*)Y)[(size_t)row*NCOLS + fcol] = __float2bfloat16(val);
        else     ((float*)Y)[(size_t)row*NCOLS + fcol] = val;
        if (STATS){ cs += val; cs2 += val*val; }
      }
    }
    if (STATS){
      cs  += __shfl_xor(cs, 16);  cs  += __shfl_xor(cs, 32);
      cs2 += __shfl_xor(cs2, 16); cs2 += __shfl_xor(cs2, 32);
      if (l < 16){ part[(size_t)mb*512 + fcol] = cs; part[(size_t)mb*512 + 256 + fcol] = cs2; }
    }
  }
}

// ---------------- edge combiners ----------------
__global__ void combine2(const bf16* __restrict__ SR, bf16* __restrict__ Y){
  int i = blockIdx.x*256 + threadIdx.x;   // 7936*32 chunks
  int row = i >> 5, c8 = (i & 31)*8;
  int b = row / NEDGE, e = row % NEDGE;
  int rc = e / 31, jj = e % 31;
  int sn = jj + (jj >= rc);
  bf16x8 s8 = *reinterpret_cast<const bf16x8*>(SR + (size_t)(b*NNODES + sn)*512 + c8);
  bf16x8 r8 = *reinterpret_cast<const bf16x8*>(SR + (size_t)(b*NNODES + rc)*512 + 256 + c8);
  bf16x8 o;
  #pragma unroll
  for (int k = 0; k < 8; k++){
    float v = bfu2f((unsigned short)s8[k]) + bfu2f((unsigned short)r8[k]);
    v = eluf(v);
    __hip_bfloat16 h = __float2bfloat16(v);
    o[k] = *reinterpret_cast<short*>(&h);
  }
  *reinterpret_cast<bf16x8*>(Y + (size_t)row*256 + c8) = o;
}

__global__ void combine4(const bf16* __restrict__ SR, const float* __restrict__ Z, bf16* __restrict__ Y){
  int i = blockIdx.x*256 + threadIdx.x;
  int row = i >> 5, c8 = (i & 31)*8;
  int b = row / NEDGE, e = row % NEDGE;
  int rc = e / 31, jj = e % 31;
  int sn = jj + (jj >= rc);
  bf16x8 s8 = *reinterpret_cast<const bf16x8*>(SR + (size_t)(b*NNODES + sn)*512 + c8);
  bf16x8 r8 = *reinterpret_cast<const bf16x8*>(SR + (size_t)(b*NNODES + rc)*512 + 256 + c8);
  const float* zp = Z + (size_t)row*256 + c8;
  float4 z0 = *reinterpret_cast<const float4*>(zp);
  float4 z1 = *reinterpret_cast<const float4*>(zp+4);
  float zz[8] = {z0.x,z0.y,z0.z,z0.w,z1.x,z1.y,z1.z,z1.w};
  bf16x8 o;
  #pragma unroll
  for (int k = 0; k < 8; k++){
    float v = bfu2f((unsigned short)s8[k]) + bfu2f((unsigned short)r8[k]) + zz[k];
    v = eluf(v);
    __hip_bfloat16 h = __float2bfloat16(v);
    o[k] = *reinterpret_cast<short*>(&h);
  }
  *reinterpret_cast<bf16x8*>(Y + (size_t)row*256 + c8) = o;
}

// ---------------- batchnorm finalize/apply ----------------
__global__ void bn_finalize(const float* __restrict__ part, int nb, const float* __restrict__ g,
                            const float* __restrict__ be, float* __restrict__ prm, float nrows){
  int f = threadIdx.x;
  float s = 0.f, s2 = 0.f;
  for (int i = 0; i < nb; i++){ s += part[(size_t)i*512+f]; s2 += part[(size_t)i*512+256+f]; }
  float m = s / nrows, var = s2 / nrows - m*m;
  float sc = g[f] * rsqrtf(var + EPSV);
  prm[f] = sc; prm[256+f] = be[f] - m*sc;
}
__global__ void bn_apply(const float* __restrict__ Y, const float* __restrict__ prm, bf16* __restrict__ X){
  int i = blockIdx.x*256 + threadIdx.x;    // 7936*32 chunks of 8
  int c8 = (i & 31)*8;
  const float* yp = Y + (size_t)i*8;
  float4 a0 = *reinterpret_cast<const float4*>(yp);
  float4 a1 = *reinterpret_cast<const float4*>(yp+4);
  float4 s0 = *reinterpret_cast<const float4*>(prm + c8);
  float4 s1 = *reinterpret_cast<const float4*>(prm + c8 + 4);
  float4 h0 = *reinterpret_cast<const float4*>(prm + 256 + c8);
  float4 h1 = *reinterpret_cast<const float4*>(prm + 256 + c8 + 4);
  float vals[8] = {a0.x*s0.x+h0.x, a0.y*s0.y+h0.y, a0.z*s0.z+h0.z, a0.w*s0.w+h0.w,
                   a1.x*s1.x+h1.x, a1.y*s1.y+h1.y, a1.z*s1.z+h1.z, a1.w*s1.w+h1.w};
  bf16x8 o;
  #pragma unroll
  for (int k = 0; k < 8; k++){
    __hip_bfloat16 h = __float2bfloat16(vals[k]);
    o[k] = *reinterpret_cast<short*>(&h);
  }
  *reinterpret_cast<bf16x8*>(X + (size_t)i*8) = o;
}

// ---------------- incoming = segment-sum over 31 edges / N ----------------
__global__ void seg_incoming(const bf16* __restrict__ X2, float* __restrict__ inc){
  int bn = blockIdx.x; int b = bn >> 5, n = bn & 31;
  int f = threadIdx.x;
  const bf16* p = X2 + (size_t)(b*NEDGE + n*31)*256 + f;
  float s = 0.f;
  for (int j = 0; j < 31; j++) s += __bfloat162float(p[j*256]);
  inc[bn*256 + f] = s * (1.f/32.f);
}

// ---------------- fc + softmax (prob out, rel_type to ws) ----------------
__global__ void fc_softmax(const bf16* __restrict__ X4, const float* __restrict__ fcw, const float* __restrict__ fcb,
                           const float* __restrict__ gumbel, float* __restrict__ prob_out, float* __restrict__ rt){
  int r = blockIdx.x*256 + threadIdx.x;
  if (r >= ROWS_E) return;
  float l0 = fcb[0], l1 = fcb[1], l2 = fcb[2], l3 = fcb[3];
  const bf16* xr = X4 + (size_t)r*256;
  for (int c = 0; c < 256; c += 8){
    uint4 u = *reinterpret_cast<const uint4*>(xr + c);
    unsigned uu[4] = {u.x, u.y, u.z, u.w};
    #pragma unroll
    for (int q = 0; q < 4; q++){
      float x0 = bfu2f((unsigned short)(uu[q] & 0xffff));
      float x1 = bfu2f((unsigned short)(uu[q] >> 16));
      int cc = c + 2*q;
      float4 w0 = *reinterpret_cast<const float4*>(fcw + cc*4);
      float4 w1 = *reinterpret_cast<const float4*>(fcw + (cc+1)*4);
      l0 += x0*w0.x + x1*w1.x; l1 += x0*w0.y + x1*w1.y;
      l2 += x0*w0.z + x1*w1.z; l3 += x0*w0.w + x1*w1.w;
    }
  }
  float mx = fmaxf(fmaxf(l0,l1), fmaxf(l2,l3));
  float e0 = __expf(l0-mx), e1 = __expf(l1-mx), e2 = __expf(l2-mx), e3 = __expf(l3-mx);
  float inv = 1.f / (e0+e1+e2+e3);
  prob_out[(size_t)r*4+0] = e0*inv; prob_out[(size_t)r*4+1] = e1*inv;
  prob_out[(size_t)r*4+2] = e2*inv; prob_out[(size_t)r*4+3] = e3*inv;
  float4 gv = *reinterpret_cast<const float4*>(gumbel + (size_t)r*4);
  float t0 = (l0+gv.x)*2.f, t1 = (l1+gv.y)*2.f, t2 = (l2+gv.z)*2.f, t3 = (l3+gv.w)*2.f;
  float mx2 = fmaxf(fmaxf(t0,t1), fmaxf(t2,t3));
  float f0 = __expf(t0-mx2), f1 = __expf(t1-mx2), f2 = __expf(t2-mx2), f3 = __expf(t3-mx2);
  float inv2 = 1.f / (f0+f1+f2+f3);
  rt[(size_t)r*4+0] = f0*inv2; rt[(size_t)r*4+1] = f1*inv2;
  rt[(size_t)r*4+2] = f2*inv2; rt[(size_t)r*4+3] = f3*inv2;
}

// ---------------- fused decoder message passing v10 ----------------
// S/R precomputed by dec_sr (S pre-swizzled in global). Per kk: one __syncthreads
// (drains prefetch), issue global_load_lds for kk+1 into the other buffer, then
// fragment-direct MFMA on current buffer. Double-buffered; 1 barrier/kk.
__global__ __launch_bounds__(256,4) void decoder_msg(
    const float* __restrict__ data, const float* __restrict__ rt,
    const unsigned short* __restrict__ SRg, const bf16* __restrict__ mw2T,
    const float* __restrict__ mb2, bf16* __restrict__ Aaug){
  __shared__ __align__(16) char Sbuf[2][16384];
  __shared__ __align__(16) char Rbuf[2][1024];
  __shared__ __align__(16) float rts_s[64][4];
  __shared__ __align__(16) float aggl[2][256];
  int bx = blockIdx.x;
  int bt = bx >> 4, rg = bx & 15;
  int b = bt / TSTEPS, t = bt % TSTEPS;
  int n0 = rg * 2;
  int tid = threadIdx.x;
  int w = tid >> 6, l = tid & 63, l15 = l & 15, lq = l >> 4;

  if (tid >= 64 && tid < 128){
    int r = tid - 64;
    int n = n0 + (r >> 5), j = r & 31;
    float4 rv = make_float4(0.f,0.f,0.f,0.f);
    if (j < 31) rv = *reinterpret_cast<const float4*>(rt + ((size_t)(b*NEDGE + n*31 + j))*4);
    *reinterpret_cast<float4*>(&rts_s[r][0]) = rv;
  }
  for (int i = tid; i < 512; i += 256) ((float*)aggl)[i] = 0.f;

  // prologue: stage S/R for kk=1 into buffer 0
  {
    const char* g = reinterpret_cast<const char*>(SRg) + (size_t)bt*32768;
    #pragma unroll
    for (int i = 0; i < 4; i++)
      gload16(g + (w*4+i)*1024 + l*16, Sbuf[0] + (w*4+i)*1024);
    if (w == 0)
      gload16(g + 16384 + n0*512 + l*16, Rbuf[0]);
  }

  int cur = 0;
  for (int kk = 1; kk < 4; kk++){
    __syncthreads();   // drains vmcnt: S/R[kk] resident; also syncs aggl writes
    if (kk < 3){
      const char* g = reinterpret_cast<const char*>(SRg) + ((size_t)kk*NBT + bt)*32768;
      #pragma unroll
      for (int i = 0; i < 4; i++)
        gload16(g + (w*4+i)*1024 + l*16, Sbuf[cur^1] + (w*4+i)*1024);
      if (w == 0)
        gload16(g + 16384 + n0*512 + l*16, Rbuf[cur^1]);
    }

    f32x4 acc[4][4];
    #pragma unroll
    for (int m = 0; m < 4; m++)
      #pragma unroll
      for (int nt = 0; nt < 4; nt++) acc[m][nt] = (f32x4){0.f,0.f,0.f,0.f};
    const bf16* wk = mw2T + (size_t)kk*65536;
    const char* Sb = Sbuf[cur];
    const char* Rb = Rbuf[cur];
    for (int s = 0; s < 8; s++){
      int c0 = s*32 + lq*8;
      bf16x8 bfr[4];
      #pragma unroll
      for (int nt = 0; nt < 4; nt++){
        int fcol = w*64 + nt*16 + l15;
        bfr[nt] = *reinterpret_cast<const bf16x8*>(wk + (size_t)fcol*256 + c0);
      }
      // hoist R for this k-slice (both receivers), unpack to f32
      float Rl0[8], Rl1[8];
      {
        bf16x8 r0 = *reinterpret_cast<const bf16x8*>(Rb + 2*c0);
        bf16x8 r1 = *reinterpret_cast<const bf16x8*>(Rb + 512 + 2*c0);
        #pragma unroll
        for (int j = 0; j < 8; j++){
          Rl0[j] = bfu2f((unsigned short)r0[j]);
          Rl1[j] = bfu2f((unsigned short)r1[j]);
        }
      }
      #pragma unroll
      for (int m = 0; m < 4; m++){
        const int rgm = m >> 1;
        int aj = (m & 1)*16 + l15;
        int recvn = n0 + rgm;
        int sv = aj + (aj >= recvn);
        if (sv > 31) sv = 31;              // pad row: garbage OK (rt=0)
        bf16x8 sr8 = *reinterpret_cast<const bf16x8*>(Sb + sv*512 + ((2*c0) ^ ((sv&7)<<4)));
        float a[8];
        #pragma unroll
        for (int j = 0; j < 8; j++){
          float s2 = bfu2f((unsigned short)sr8[j]);
          a[j] = fmaxf(s2 + (rgm == 0 ? Rl0[j] : Rl1[j]), 0.f);
        }
        union { unsigned u[4]; bf16x8 v; } af;
        af.u[0] = cvt_pk_bf16(a[0], a[1]);
        af.u[1] = cvt_pk_bf16(a[2], a[3]);
        af.u[2] = cvt_pk_bf16(a[4], a[5]);
        af.u[3] = cvt_pk_bf16(a[6], a[7]);
        #pragma unroll
        for (int nt = 0; nt < 4; nt++)
          acc[m][nt] = __builtin_amdgcn_mfma_f32_16x16x32_bf16(af.v, bfr[nt], acc[m][nt], 0, 0, 0);
      }
    }
    // epilogue: relu(+b2) * rel_type, column-reduce into per-receiver agg
    #pragma unroll
    for (int m = 0; m < 4; m++){
      int g = m >> 1;
      #pragma unroll
      for (int nt = 0; nt < 4; nt++){
        int fcol = w*64 + nt*16 + l15;
        float bv = mb2[kk*256 + fcol];
        float ssum = 0.f;
        #pragma unroll
        for (int v = 0; v < 4; v++){
          int rowa = m*16 + lq*4 + v;
          float msg = fmaxf(acc[m][nt][v] + bv, 0.f);
          ssum += msg * rts_s[rowa][kk];
        }
        ssum += __shfl_xor(ssum, 16);
        ssum += __shfl_xor(ssum, 32);
        if (lq == 0) aggl[g][fcol] += ssum;
      }
    }
    cur ^= 1;
  }
  __syncthreads();

  // write aug rows: [data(4) | agg(256) | pad(28)] bf16, K=288
  for (int i = tid; i < 2*288; i += 256){
    int g = i / 288, c = i % 288;
    float val;
    if (c < 4)        val = data[((size_t)(b*NNODES + n0 + g)*TSTEPS + t)*4 + c];
    else if (c < 260) val = aggl[g][c-4];
    else              val = 0.f;
    Aaug[(size_t)(bt*NNODES + n0 + g)*288 + c] = __float2bfloat16(val);
  }
}

// ---------------- final: p3 = P2 @ ow3 + ob3 ; out = data + p3 (t<48) ----------------
__global__ void final_out(const bf16* __restrict__ P2, const float* __restrict__ ow3,
                          const float* __restrict__ ob3, const float* __restrict__ data,
                          float* __restrict__ out){
  int r = blockIdx.x*256 + threadIdx.x;
  if (r >= ROWS_OUT) return;
  int bt = r >> 5, n = r & 31;
  int b = bt / TSTEPS, t = bt % TSTEPS;
  float a0 = ob3[0], a1 = ob3[1], a2 = ob3[2], a3 = ob3[3];
  const bf16* pr = P2 + (size_t)r*256;
  for (int c = 0; c < 256; c += 8){
    uint4 u = *reinterpret_cast<const uint4*>(pr + c);
    unsigned uu[4] = {u.x, u.y, u.z, u.w};
    #pragma unroll
    for (int q = 0; q < 4; q++){
      float x0 = bfu2f((unsigned short)(uu[q] & 0xffff));
      float x1 = bfu2f((unsigned short)(uu[q] >> 16));
      int cc = c + 2*q;
      float4 w0 = *reinterpret_cast<const float4*>(ow3 + cc*4);
      float4 w1 = *reinterpret_cast<const float4*>(ow3 + (cc+1)*4);
      a0 += x0*w0.x + x1*w1.x; a1 += x0*w0.y + x1*w1.y;
      a2 += x0*w0.z + x1*w1.z; a3 += x0*w0.w + x1*w1.w;
    }
  }
  if (t < TSTEPS-1){
    float4 dv = *reinterpret_cast<const float4*>(data + ((size_t)(b*NNODES + n)*TSTEPS + t)*4);
    float4 o; o.x = dv.x + a0; o.y = dv.y + a1; o.z = dv.z + a2; o.w = dv.w + a3;
    *reinterpret_cast<float4*>(out + ((size_t)(b*NNODES + n)*(TSTEPS-1) + t)*4) = o;
  }
}

// ---------------- launcher ----------------
extern "C" void kernel_launch(void* const* d_in, const int* in_sizes, int n_in,
                              void* d_out, int out_size, void* d_ws, size_t ws_size,
                              hipStream_t stream){
  const float* data    = (const float*)d_in[0];
  const float* gumbel  = (const float*)d_in[1];
  const float* e1_w1=(const float*)d_in[4],  *e1_b1=(const float*)d_in[5],
             * e1_w2=(const float*)d_in[6],  *e1_b2=(const float*)d_in[7],
             * e1_g =(const float*)d_in[8],  *e1_be=(const float*)d_in[9];
  const float* e2_w1=(const float*)d_in[10], *e2_b1=(const float*)d_in[11],
             * e2_w2=(const float*)d_in[12], *e2_b2=(const float*)d_in[13],
             * e2_g =(const float*)d_in[14], *e2_be=(const float*)d_in[15];
  const float* e3_w1=(const float*)d_in[16], *e3_b1=(const float*)d_in[17],
             * e3_w2=(const float*)d_in[18], *e3_b2=(const float*)d_in[19],
             * e3_g =(const float*)d_in[20], *e3_be=(const float*)d_in[21];
  const float* e4_w1=(const float*)d_in[22], *e4_b1=(const float*)d_in[23],
             * e4_w2=(const float*)d_in[24], *e4_b2=(const float*)d_in[25],
             * e4_g =(const float*)d_in[26], *e4_be=(const float*)d_in[27];
  const float* fc_w=(const float*)d_in[28], *fc_b=(const float*)d_in[29];
  const float* mw1=(const float*)d_in[30], *mb1=(const float*)d_in[31];
  const float* mw2=(const float*)d_in[32], *mb2=(const float*)d_in[33];
  const float* ow1=(const float*)d_in[34], *ob1=(const float*)d_in[35];
  const float* ow2=(const float*)d_in[36], *ob2=(const float*)d_in[37];
  const float* ow3=(const float*)d_in[38], *ob3=(const float*)d_in[39];

  char* ws = (char*)d_ws;
  size_t off = 0;
  auto alloc = [&](size_t bytes)->void*{ void* p = ws + off; off = (off + bytes + 255) & ~(size_t)255; return p; };
  bf16* W2ABT= (bf16*)alloc((size_t)131072*2);
  bf16* W2BT = (bf16*)alloc((size_t)65536*2);
  bf16* W4ABT= (bf16*)alloc((size_t)131072*2);
  bf16* W4CT = (bf16*)alloc((size_t)65536*2);
  bf16* W4BT = (bf16*)alloc((size_t)65536*2);
  bf16* MW2T = (bf16*)alloc((size_t)262144*2);
  bf16* OW1T = (bf16*)alloc((size_t)73728*2);
  bf16* OW2T = (bf16*)alloc((size_t)65536*2);
  float* BIAS2=(float*)alloc((size_t)512*4);
  float* BIAS4=(float*)alloc((size_t)512*4);
  float* ZEROB=(float*)alloc((size_t)256*4);
  bf16* X1   = (bf16*)alloc((size_t)65536*2);
  float* HS  = (float*)alloc((size_t)65536*4);
  bf16* X3   = (bf16*)alloc((size_t)65536*2);
  bf16* SR2  = (bf16*)alloc((size_t)131072*2);
  bf16* SR4  = (bf16*)alloc((size_t)131072*2);
  float* Z4  = (float*)alloc((size_t)7936*256*4);
  bf16* YBF  = (bf16*)alloc((size_t)12544*256*2);
  float* YF32= (float*)alloc((size_t)7936*256*4);
  bf16* X2   = (bf16*)alloc((size_t)7936*256*2);
  bf16* X4   = (bf16*)alloc((size_t)7936*256*2);
  bf16* P2   = (bf16*)alloc((size_t)12544*256*2);
  float* INC = (float*)alloc((size_t)65536*4);
  float* RT  = (float*)alloc((size_t)7936*4*4);
  float* PART= (float*)alloc((size_t)248*512*4);
  float* PRM = (float*)alloc((size_t)512*4);
  bf16* AAUG = (bf16*)alloc((size_t)12544*288*2);
  unsigned short* SRG = (unsigned short*)alloc((size_t)3*NBT*16384*2);  // 38.5MB

  float* out = (float*)d_out;
  float* prob_out = out + 49152;

  prep_weights<<<3365,256,0,stream>>>(e2_w1,e2_w2,e4_w1,e4_w2,mw2,ow1,ow2,e2_b1,e4_b1,
                                      W2ABT,W2BT,W4ABT,W4CT,W4BT,MW2T,OW1T,OW2T,BIAS2,BIAS4,ZEROB);
  dec_sr<<<NBT,256,0,stream>>>(data, mw1, mb1, SRG);
  small_mlp<196><<<256,256,0,stream>>>(data, e1_w1,e1_b1,e1_w2,e1_b2, HS);
  bn_small<<<1,256,0,stream>>>(HS, e1_g, e1_be, X1);
  gemm_mfma<256,512,0,true,32,false><<<8,256,0,stream>>>(X1, W2ABT, BIAS2, SR2, nullptr);
  combine2<<<992,256,0,stream>>>(SR2, YBF);
  gemm_mfma<256,256,2,false,32,true><<<248,256,0,stream>>>(YBF, W2BT, e2_b2, YF32, PART);
  bn_finalize<<<1,256,0,stream>>>(PART, 248, e2_g, e2_be, PRM, 7936.f);
  bn_apply<<<992,256,0,stream>>>(YF32, PRM, X2);
  seg_incoming<<<256,256,0,stream>>>(X2, INC);
  small_mlp<256><<<256,256,0,stream>>>(INC, e3_w1,e3_b1,e3_w2,e3_b2, HS);
  bn_small<<<1,256,0,stream>>>(HS, e3_g, e3_be, X3);
  gemm_mfma<256,512,0,true,32,false><<<8,256,0,stream>>>(X3, W4ABT, BIAS4, SR4, nullptr);
  gemm_mfma<256,256,0,false,32,false><<<248,256,0,stream>>>(X2, W4CT, ZEROB, Z4, nullptr);
  combine4<<<992,256,0,stream>>>(SR4, Z4, YBF);
  gemm_mfma<256,256,2,false,32,true><<<248,256,0,stream>>>(YBF, W4BT, e4_b2, YF32, PART);
  bn_finalize<<<1,256,0,stream>>>(PART, 248, e4_g, e4_be, PRM, 7936.f);
  bn_apply<<<992,256,0,stream>>>(YF32, PRM, X4);
  fc_softmax<<<31,256,0,stream>>>(X4, fc_w, fc_b, gumbel, prob_out, RT);
  decoder_msg<<<6272,256,0,stream>>>(data, RT, SRG, MW2T, mb2, AAUG);
  gemm_mfma<288,256,1,true,32,false><<<392,256,0,stream>>>(AAUG, OW1T, ob1, YBF, nullptr);
  gemm_mfma<256,256,1,true,32,false><<<392,256,0,stream>>>(YBF, OW2T, ob2, P2, nullptr);
  final_out<<<49,256,0,stream>>>(P2, ow3, ob3, data, out);
}